// Round 7
// baseline (239.471 us; speedup 1.0000x reference)
//
#include <hip/hip_runtime.h>
#include <stdint.h>

typedef __attribute__((ext_vector_type(4))) float  f32x4;
typedef __attribute__((ext_vector_type(8))) short  s16x8;
typedef __attribute__((ext_vector_type(4))) short  s16x4;

__device__ __forceinline__ unsigned short f2bf(float x) {
  union { float f; unsigned int u; } a; a.f = x;
  unsigned int lsb = (a.u >> 16) & 1u;
  a.u += 0x7fffu + lsb;                    // round-to-nearest-even
  return (unsigned short)(a.u >> 16);
}
__device__ __forceinline__ float bf2f(unsigned short h) {
  union { unsigned int u; float f; } a; a.u = ((unsigned int)h) << 16; return a.f;
}

// async global->LDS, 16B per lane. LDS dest must be wave-uniform base (+lane*16).
__device__ __forceinline__ void gload_lds16(const void* g, void* s) {
  __builtin_amdgcn_global_load_lds(
      (__attribute__((address_space(1))) void*)g,
      (__attribute__((address_space(3))) void*)s, 16, 0, 0);
}

// ---------------- K2: f32 -> bf16 (hi only) ----------------
__global__ __launch_bounds__(256) void k_convert_hi(
    const float* __restrict__ in, unsigned short* __restrict__ out, int n4) {
  int i = blockIdx.x * 256 + threadIdx.x;
  if (i < n4) {
    f32x4 v = ((const f32x4*)in)[i];
    s16x4 h;
#pragma unroll
    for (int j = 0; j < 4; j++) h[j] = (short)f2bf(v[j]);
    ((s16x4*)out)[i] = h;
  }
}

// ---------------- K3: f32 TN gemm: C[m][n] = sum_k A[m][k]*B[n][k] + bias[n] ----------------
__global__ __launch_bounds__(256) void k_gemm_f32_tn(
    const float* __restrict__ A, const float* __restrict__ Bm,
    const float* __restrict__ bias, float* __restrict__ C,
    int M, int N, int K) {
  __shared__ float As[32][33], Bs[32][33];
  int tid = threadIdx.x;
  int bm = blockIdx.x * 32, bn = blockIdx.y * 32;
  int tr = tid & 31, tq = tid >> 5;
  float acc[4] = {0.f, 0.f, 0.f, 0.f};
  for (int k0 = 0; k0 < K; k0 += 32) {
#pragma unroll
    for (int i = 0; i < 4; i++) {
      int idx = tid + i * 256;
      int r = idx >> 5, c = idx & 31;
      As[r][c] = A[(size_t)(bm + r) * K + k0 + c];
      Bs[r][c] = Bm[(size_t)(bn + r) * K + k0 + c];
    }
    __syncthreads();
#pragma unroll
    for (int kk = 0; kk < 32; kk++) {
      float b = Bs[tr][kk];
#pragma unroll
      for (int i = 0; i < 4; i++) acc[i] += As[tq * 4 + i][kk] * b;
    }
    __syncthreads();
  }
#pragma unroll
  for (int i = 0; i < 4; i++)
    C[(size_t)(bm + tq * 4 + i) * N + bn + tr] = acc[i] + bias[bn + tr];
}

// ---------------- K4: f32 NN gemm + bf16 hi/lo split output ----------------
__global__ __launch_bounds__(256) void k_gemm_f32_nn_split(
    const float* __restrict__ A, const float* __restrict__ Bm,
    unsigned short* __restrict__ Chi, unsigned short* __restrict__ Clo,
    int M, int N, int K) {
  __shared__ float As[32][33], Bs[32][33];
  int tid = threadIdx.x;
  int bm = blockIdx.x * 32, bn = blockIdx.y * 32;
  int tr = tid & 31, tq = tid >> 5;
  float acc[4] = {0.f, 0.f, 0.f, 0.f};
  for (int k0 = 0; k0 < K; k0 += 32) {
#pragma unroll
    for (int i = 0; i < 4; i++) {
      int idx = tid + i * 256;
      int r = idx >> 5, c = idx & 31;
      As[r][c] = A[(size_t)(bm + r) * K + k0 + c];
      Bs[r][c] = Bm[(size_t)(k0 + r) * N + bn + c];
    }
    __syncthreads();
#pragma unroll
    for (int kk = 0; kk < 32; kk++) {
      float b = Bs[kk][tr];
#pragma unroll
      for (int i = 0; i < 4; i++) acc[i] += As[tq * 4 + i][kk] * b;
    }
    __syncthreads();
  }
#pragma unroll
  for (int i = 0; i < 4; i++) {
    float q = acc[i];
    unsigned short hb = f2bf(q);
    size_t o = (size_t)(bm + tq * 4 + i) * N + bn + tr;
    Chi[o] = hb;
    Clo[o] = f2bf(q - bf2f(hb));
  }
}

// ---------------- K6: 3-pass split-bf16 TN gemm -> score partials ----------------
// 2-phase double-buffered pipeline: prefetch tile t+1 (A via gload_lds, B via
// reg) while computing tile t; one barrier per tile.
__global__ __launch_bounds__(256, 3) void k_gemm_scores(
    const unsigned short* __restrict__ Ah, const unsigned short* __restrict__ Al,
    const float* __restrict__ img, float* __restrict__ Sp) {
  __shared__ unsigned short Ahs[8192], Als[8192];   // 2 buf x [128][32]
  __shared__ unsigned short Bhs[4096], Bls[4096];   // 2 buf x [64][32]
  int tid = threadIdx.x, l = tid & 63, w = tid >> 6;
  int wm = w >> 1, wn = w & 1;              // 2 x 2 wave grid over 128x64 tile
  int bid = blockIdx.x;
  int xcd = bid & 7, local = bid >> 3;
  int ks = local & 1;
  int bn = (xcd * 64 + (local >> 1)) * 64;
  int kbase = ks * 512;
  float* S = Sp + (size_t)ks * 4194304;
  int lr = l & 15, lk8 = l >> 4;
  int sF = (lr >> 1) & 3;
  int srow = tid >> 2;
  int bswz = (tid & 3) ^ ((tid >> 3) & 3);
  const unsigned short* a0h = Ah + (size_t)srow * 1024 + bswz * 8;
  const unsigned short* a1h = Ah + (size_t)(64 + srow) * 1024 + bswz * 8;
  const unsigned short* a0l = Al + (size_t)srow * 1024 + bswz * 8;
  const unsigned short* a1l = Al + (size_t)(64 + srow) * 1024 + bswz * 8;
  const float* gB = img + (size_t)(bn + srow) * 1024 + (tid & 3) * 8;
  int bByte = srow * 64 + (bswz << 4);
  f32x4 acc[4][2] = {};

#define SC_SPLIT_WRITE(D, V0, V1) { \
    s16x8 h_, lw_; \
    _Pragma("unroll") \
    for (int j = 0; j < 4; j++) { \
      unsigned short hb = f2bf((V0)[j]); \
      h_[j] = (short)hb; lw_[j] = (short)f2bf((V0)[j] - bf2f(hb)); \
      unsigned short hb1 = f2bf((V1)[j]); \
      h_[j + 4] = (short)hb1; lw_[j + 4] = (short)f2bf((V1)[j] - bf2f(hb1)); \
    } \
    *(s16x8*)((char*)Bhs + (D) * 4096 + bByte) = h_; \
    *(s16x8*)((char*)Bls + (D) * 4096 + bByte) = lw_; }

#define SC_STEP(T, CUR, NXT) { \
    bool pf = (T) + 1 < 16; \
    f32x4 v0n = {}, v1n = {}; \
    if (pf) { \
      int kn = kbase + ((T) + 1) * 32; \
      v0n = *(const f32x4*)(gB + kn); \
      v1n = *(const f32x4*)(gB + kn + 4); \
      gload_lds16(a0h + kn, &Ahs[(NXT) * 4096 + w * 512]); \
      gload_lds16(a1h + kn, &Ahs[(NXT) * 4096 + 2048 + w * 512]); \
      gload_lds16(a0l + kn, &Als[(NXT) * 4096 + w * 512]); \
      gload_lds16(a1l + kn, &Als[(NXT) * 4096 + 2048 + w * 512]); \
    } \
    s16x8 ah[4], al4[4], bh[2], bl[2]; \
    _Pragma("unroll") \
    for (int i = 0; i < 4; i++) { \
      int byte = (CUR) * 8192 + (wm * 64 + i * 16 + lr) * 64 + ((lk8 ^ sF) << 4); \
      ah[i] = *(const s16x8*)((const char*)Ahs + byte); \
      al4[i] = *(const s16x8*)((const char*)Als + byte); \
    } \
    _Pragma("unroll") \
    for (int j = 0; j < 2; j++) { \
      int byte = (CUR) * 4096 + (wn * 32 + j * 16 + lr) * 64 + ((lk8 ^ sF) << 4); \
      bh[j] = *(const s16x8*)((const char*)Bhs + byte); \
      bl[j] = *(const s16x8*)((const char*)Bls + byte); \
    } \
    _Pragma("unroll") \
    for (int i = 0; i < 4; i++) \
      _Pragma("unroll") \
      for (int j = 0; j < 2; j++) { \
        acc[i][j] = __builtin_amdgcn_mfma_f32_16x16x32_bf16(ah[i], bh[j], acc[i][j], 0, 0, 0); \
        acc[i][j] = __builtin_amdgcn_mfma_f32_16x16x32_bf16(ah[i], bl[j], acc[i][j], 0, 0, 0); \
        acc[i][j] = __builtin_amdgcn_mfma_f32_16x16x32_bf16(al4[i], bh[j], acc[i][j], 0, 0, 0); \
      } \
    if (pf) SC_SPLIT_WRITE(NXT, v0n, v1n); \
    __syncthreads(); }

  // prologue: stage tile 0 into buf 0
  {
    f32x4 v0 = *(const f32x4*)(gB + kbase);
    f32x4 v1 = *(const f32x4*)(gB + kbase + 4);
    gload_lds16(a0h + kbase, &Ahs[w * 512]);
    gload_lds16(a1h + kbase, &Ahs[2048 + w * 512]);
    gload_lds16(a0l + kbase, &Als[w * 512]);
    gload_lds16(a1l + kbase, &Als[2048 + w * 512]);
    SC_SPLIT_WRITE(0, v0, v1);
    __syncthreads();
  }
#pragma unroll 1
  for (int t = 0; t < 16; t += 2) {
    SC_STEP(t, 0, 1);
    SC_STEP(t + 1, 1, 0);
  }
  int rh = (l >> 4) * 4;
#pragma unroll
  for (int i = 0; i < 4; i++)
#pragma unroll
    for (int q = 0; q < 4; q++) {
      int gm = wm * 64 + i * 16 + rh + q;
#pragma unroll
      for (int j = 0; j < 2; j++) {
        int gn = bn + wn * 32 + j * 16 + lr;
        S[(size_t)gm * 32768 + gn] = acc[i][j][q];
      }
    }
#undef SC_STEP
#undef SC_SPLIT_WRITE
}

// ---------------- K7: softmax over r (256): sum K-partials, *1/32, f32 -> bf16 [b][l][r] ----------------
__global__ __launch_bounds__(256) void k_softmax(
    const float* __restrict__ S0, unsigned short* __restrict__ P) {
  const float* S1 = S0 + 4194304;
  int w = threadIdx.x >> 6, l = threadIdx.x & 63;
  int row = blockIdx.x * 4 + w;            // row = l*128 + b, 16384 rows
  f32x4 x0 = ((const f32x4*)(S0 + (size_t)row * 256))[l];
  f32x4 x1 = ((const f32x4*)(S1 + (size_t)row * 256))[l];
  f32x4 x;
#pragma unroll
  for (int j = 0; j < 4; j++) x[j] = x0[j] + x1[j];
  float m = fmaxf(fmaxf(x[0], x[1]), fmaxf(x[2], x[3]));
#pragma unroll
  for (int s = 1; s < 64; s <<= 1) m = fmaxf(m, __shfl_xor(m, s, 64));
  f32x4 e;
  float sum = 0.f;
#pragma unroll
  for (int j = 0; j < 4; j++) { e[j] = __expf(x[j] - m); sum += e[j]; }
#pragma unroll
  for (int s = 1; s < 64; s <<= 1) sum += __shfl_xor(sum, s, 64);
  float sc = 0.03125f / sum;
  s16x4 o;
#pragma unroll
  for (int j = 0; j < 4; j++) o[j] = (short)f2bf(e[j] * sc);
  int bb = row & 127, ll = row >> 7;
  ((s16x4*)(P + ((size_t)bb * 128 + ll) * 256))[l] = o;
}

// ---------------- K9: ctx[b][l][d] = sum_r attenB[b][l][r] * img[b][r][d] ----------------
// 2-phase pipeline; A async-staged, B reg-staged f32->bf16 transpose with swizzle.
__global__ __launch_bounds__(256, 3) void k_gemm_ctx(
    const unsigned short* __restrict__ P, const float* __restrict__ img,
    unsigned short* __restrict__ Cp) {
  __shared__ unsigned short As[8192];   // 2 buf x [128 l][32 r], src-preswizzled
  __shared__ unsigned short Bs[8192];   // 2 buf x [128 d][32 r], chunk^((d>>1)&3)
  int tid = threadIdx.x, l = tid & 63, w = tid >> 6;
  int wm = w >> 1, wn = w & 1;
  int rid = blockIdx.x;
  int xcd = rid & 7, lid = rid >> 3;
  int b = xcd * 16 + (lid >> 3);
  int d0 = (lid & 7) * 128;
  const unsigned short* Pb = P + (size_t)b * 32768;
  int lr = l & 15, lk8 = l >> 4;
  int sF = (lr >> 1) & 3;
  int u = tid & 15, dc = tid >> 4;
  int srow = tid >> 2;
  int bswz = (tid & 3) ^ ((tid >> 3) & 3);
  const unsigned short* p0 = Pb + (size_t)srow * 256 + bswz * 8;
  const unsigned short* p1 = Pb + (size_t)(64 + srow) * 256 + bswz * 8;
  const float* gV = img + (size_t)(b * 256 + 2 * u) * 1024 + d0 + dc * 8;
  f32x4 acc[4][4] = {};

#define CTX_WRITE_B(D, A0, A1, B0, B1) { \
    _Pragma("unroll") \
    for (int j = 0; j < 8; j++) { \
      float x0 = (j < 4) ? (A0)[j & 3] : (A1)[j & 3]; \
      float x1 = (j < 4) ? (B0)[j & 3] : (B1)[j & 3]; \
      int dd = dc * 8 + j; \
      unsigned int w32 = (unsigned int)f2bf(x0) | ((unsigned int)f2bf(x1) << 16); \
      int byte = (D) * 8192 + dd * 64 + ((4 * u) ^ (((dd >> 1) & 3) << 4)); \
      *(unsigned int*)((char*)Bs + byte) = w32; \
    } }

#define CTX_STEP(T, CUR, NXT) { \
    bool pf = (T) + 1 < 8; \
    f32x4 a0n = {}, a1n = {}, b0n = {}, b1n = {}; \
    if (pf) { \
      int kn = ((T) + 1) * 32; \
      const float* gs = gV + (size_t)kn * 1024; \
      a0n = *(const f32x4*)gs; \
      a1n = *(const f32x4*)(gs + 4); \
      b0n = *(const f32x4*)(gs + 1024); \
      b1n = *(const f32x4*)(gs + 1028); \
      gload_lds16(p0 + kn, &As[(NXT) * 4096 + w * 512]); \
      gload_lds16(p1 + kn, &As[(NXT) * 4096 + 2048 + w * 512]); \
    } \
    s16x8 af[4], bf[4]; \
    _Pragma("unroll") \
    for (int i = 0; i < 4; i++) { \
      int byte = (CUR) * 8192 + (wm * 64 + i * 16 + lr) * 64 + ((lk8 ^ sF) << 4); \
      af[i] = *(const s16x8*)((const char*)As + byte); \
    } \
    _Pragma("unroll") \
    for (int j = 0; j < 4; j++) { \
      int n = wn * 64 + j * 16 + lr; \
      int byte = (CUR) * 8192 + n * 64 + ((lk8 ^ sF) << 4); \
      bf[j] = *(const s16x8*)((const char*)Bs + byte); \
    } \
    _Pragma("unroll") \
    for (int i = 0; i < 4; i++) \
      _Pragma("unroll") \
      for (int j = 0; j < 4; j++) \
        acc[i][j] = __builtin_amdgcn_mfma_f32_16x16x32_bf16(af[i], bf[j], acc[i][j], 0, 0, 0); \
    if (pf) CTX_WRITE_B(NXT, a0n, a1n, b0n, b1n); \
    __syncthreads(); }

  // prologue: stage tile 0 into buf 0
  {
    f32x4 a0 = *(const f32x4*)gV;
    f32x4 a1 = *(const f32x4*)(gV + 4);
    f32x4 b0 = *(const f32x4*)(gV + 1024);
    f32x4 b1 = *(const f32x4*)(gV + 1028);
    gload_lds16(p0, &As[w * 512]);
    gload_lds16(p1, &As[2048 + w * 512]);
    CTX_WRITE_B(0, a0, a1, b0, b1);
    __syncthreads();
  }
#pragma unroll 1
  for (int t = 0; t < 8; t += 2) {
    CTX_STEP(t, 0, 1);
    CTX_STEP(t + 1, 1, 0);
  }
  int rh = (l >> 4) * 4;
#pragma unroll
  for (int i = 0; i < 4; i++)
#pragma unroll
    for (int q = 0; q < 4; q++) {
      int gm = wm * 64 + i * 16 + rh + q;
#pragma unroll
      for (int j = 0; j < 4; j++) {
        int gn = wn * 64 + j * 16 + lr;
        Cp[((size_t)b * 128 + gm) * 1024 + d0 + gn] = f2bf(acc[i][j][q]);
      }
    }
#undef CTX_STEP
#undef CTX_WRITE_B
}

// ---------------- K10: out[m][n] = sum_k ctx[m][k]*Wv[n][k] + bv[n]/32 ----------------
// 2-phase pipeline, both operands async-staged. M=16384, N=1024, K=1024.
__global__ __launch_bounds__(256, 3) void k_gemm_out(
    const unsigned short* __restrict__ A, const unsigned short* __restrict__ Bm,
    const float* __restrict__ bv, float* __restrict__ Out) {
  __shared__ unsigned short As[8192], Bs[8192];   // 2 buf x [128][32]
  int tid = threadIdx.x, l = tid & 63, w = tid >> 6;
  int wm = w >> 1, wn = w & 1;
  int rid = blockIdx.x;
  int xcd = rid & 7, lid = rid >> 3;
  int bm = (xcd * 16 + (lid >> 3)) * 128;
  int bn = (lid & 7) * 128;
  int lr = l & 15, lk8 = l >> 4;
  int sF = (lr >> 1) & 3;
  int srow = tid >> 2;
  int swz = (tid & 3) ^ ((tid >> 3) & 3);
  const unsigned short* a0 = A + (size_t)(bm + srow) * 1024 + swz * 8;
  const unsigned short* a1 = A + (size_t)(bm + 64 + srow) * 1024 + swz * 8;
  const unsigned short* b0 = Bm + (size_t)(bn + srow) * 1024 + swz * 8;
  const unsigned short* b1 = Bm + (size_t)(bn + 64 + srow) * 1024 + swz * 8;
  f32x4 acc[4][4] = {};

#define OUT_STAGE(KN, D) { \
    gload_lds16(a0 + (KN), &As[(D) * 4096 + w * 512]); \
    gload_lds16(a1 + (KN), &As[(D) * 4096 + 2048 + w * 512]); \
    gload_lds16(b0 + (KN), &Bs[(D) * 4096 + w * 512]); \
    gload_lds16(b1 + (KN), &Bs[(D) * 4096 + 2048 + w * 512]); }

#define OUT_STEP(T, CUR, NXT) { \
    if ((T) + 1 < 32) OUT_STAGE(((T) + 1) * 32, NXT); \
    s16x8 af[4], bf[4]; \
    _Pragma("unroll") \
    for (int i = 0; i < 4; i++) { \
      int byte = (CUR) * 8192 + (wm * 64 + i * 16 + lr) * 64 + ((lk8 ^ sF) << 4); \
      af[i] = *(const s16x8*)((const char*)As + byte); \
    } \
    _Pragma("unroll") \
    for (int i = 0; i < 4; i++) { \
      int byte = (CUR) * 8192 + (wn * 64 + i * 16 + lr) * 64 + ((lk8 ^ sF) << 4); \
      bf[i] = *(const s16x8*)((const char*)Bs + byte); \
    } \
    _Pragma("unroll") \
    for (int i = 0; i < 4; i++) \
      _Pragma("unroll") \
      for (int j = 0; j < 4; j++) \
        acc[i][j] = __builtin_amdgcn_mfma_f32_16x16x32_bf16(af[i], bf[j], acc[i][j], 0, 0, 0); \
    __syncthreads(); }

  OUT_STAGE(0, 0);
  __syncthreads();
#pragma unroll 1
  for (int t = 0; t < 32; t += 2) {
    OUT_STEP(t, 0, 1);
    OUT_STEP(t + 1, 1, 0);
  }
  int rh = (l >> 4) * 4;
#pragma unroll
  for (int i = 0; i < 4; i++)
#pragma unroll
    for (int q = 0; q < 4; q++) {
      int gm = bm + wm * 64 + i * 16 + rh + q;
#pragma unroll
      for (int j = 0; j < 4; j++) {
        int gn = bn + wn * 64 + j * 16 + lr;
        Out[(size_t)gm * 1024 + gn] = acc[i][j][q] + 0.03125f * bv[gn];
      }
    }
#undef OUT_STEP
#undef OUT_STAGE
}

extern "C" void kernel_launch(void* const* d_in, const int* in_sizes, int n_in,
                              void* d_out, int out_size, void* d_ws, size_t ws_size,
                              hipStream_t stream) {
  const float* cap = (const float*)d_in[0];
  const float* img = (const float*)d_in[1];
  const float* Wq  = (const float*)d_in[2];
  const float* bq  = (const float*)d_in[3];
  const float* Wk  = (const float*)d_in[4];
  // d_in[5] = bk: constant across r -> cancels in softmax. Unused.
  const float* Wv  = (const float*)d_in[6];
  const float* bv  = (const float*)d_in[7];
  float* out = (float*)d_out;

  char* ws = (char*)d_ws;
  if (ws_size < 78643200ull) return;  // fail loudly (output stays poisoned)
  float*          scores = (float*)(ws);                     // 32 MB (2 K-halves)
  unsigned short* atten  = (unsigned short*)(ws + 33554432); //  8 MB
  unsigned short* ctx    = (unsigned short*)(ws + 41943040); // 32 MB
  float*          Qb     = (float*)(ws + 75497472);          // 512 KB
  unsigned short* QWh    = (unsigned short*)(ws + 76021760); // 256 KB
  unsigned short* QWl    = (unsigned short*)(ws + 76283904); // 256 KB
  unsigned short* Wvh    = (unsigned short*)(ws + 76546048); //   2 MB

  k_convert_hi<<<1024, 256, 0, stream>>>(Wv, Wvh, 1048576 / 4);
  // Q = cap @ Wq^T + bq  (f32)
  k_gemm_f32_tn<<<dim3(4, 32), 256, 0, stream>>>(cap, Wq, bq, Qb, 128, 1024, 1024);
  // QW = Q @ Wk  (f32 -> bf16 hi/lo)
  k_gemm_f32_nn_split<<<dim3(4, 32), 256, 0, stream>>>(Qb, Wk, QWh, QWl, 128, 1024, 1024);
  // score partials = QW @ img^T  (3-pass split bf16, 2-phase pipelined)
  k_gemm_scores<<<1024, 256, 0, stream>>>(QWh, QWl, img, scores);
  // atten[b][l][r] = softmax(sum of partials) / 32  (bf16)
  k_softmax<<<4096, 256, 0, stream>>>(scores, atten);
  // ctx[b][l][d] = atten[b] @ img[b]  (bf16, 2-phase pipelined)
  k_gemm_ctx<<<1024, 256, 0, stream>>>(atten, img, ctx);
  // out = ctx @ Wv^T + bv/32  (2-phase pipelined)
  k_gemm_out<<<1024, 256, 0, stream>>>(ctx, Wvh, bv, out);
}

// Round 8
// 215.833 us; speedup vs baseline: 1.1095x; 1.1095x over previous
//
#include <hip/hip_runtime.h>
#include <stdint.h>

typedef __attribute__((ext_vector_type(4))) float  f32x4;
typedef __attribute__((ext_vector_type(8))) short  s16x8;
typedef __attribute__((ext_vector_type(4))) short  s16x4;

__device__ __forceinline__ unsigned short f2bf(float x) {
  union { float f; unsigned int u; } a; a.f = x;
  unsigned int lsb = (a.u >> 16) & 1u;
  a.u += 0x7fffu + lsb;                    // round-to-nearest-even
  return (unsigned short)(a.u >> 16);
}
__device__ __forceinline__ float bf2f(unsigned short h) {
  union { unsigned int u; float f; } a; a.u = ((unsigned int)h) << 16; return a.f;
}

// async global->LDS, 16B per lane. LDS dest must be wave-uniform base (+lane*16).
__device__ __forceinline__ void gload_lds16(const void* g, void* s) {
  __builtin_amdgcn_global_load_lds(
      (__attribute__((address_space(1))) void*)g,
      (__attribute__((address_space(3))) void*)s, 16, 0, 0);
}

#define VMCNT(N) asm volatile("s_waitcnt vmcnt(" #N ")" ::: "memory")
#define LGKM0()  asm volatile("s_waitcnt lgkmcnt(0)" ::: "memory")
#define SBAR()   __builtin_amdgcn_s_barrier()
#define SFENCE() __builtin_amdgcn_sched_barrier(0)

// ---------------- K2: f32 -> bf16 (hi only) ----------------
__global__ __launch_bounds__(256) void k_convert_hi(
    const float* __restrict__ in, unsigned short* __restrict__ out, int n4) {
  int i = blockIdx.x * 256 + threadIdx.x;
  if (i < n4) {
    f32x4 v = ((const f32x4*)in)[i];
    s16x4 h;
#pragma unroll
    for (int j = 0; j < 4; j++) h[j] = (short)f2bf(v[j]);
    ((s16x4*)out)[i] = h;
  }
}

// ---------------- K3: f32 TN gemm: C[m][n] = sum_k A[m][k]*B[n][k] + bias[n] ----------------
__global__ __launch_bounds__(256) void k_gemm_f32_tn(
    const float* __restrict__ A, const float* __restrict__ Bm,
    const float* __restrict__ bias, float* __restrict__ C,
    int M, int N, int K) {
  __shared__ float As[32][33], Bs[32][33];
  int tid = threadIdx.x;
  int bm = blockIdx.x * 32, bn = blockIdx.y * 32;
  int tr = tid & 31, tq = tid >> 5;
  float acc[4] = {0.f, 0.f, 0.f, 0.f};
  for (int k0 = 0; k0 < K; k0 += 32) {
#pragma unroll
    for (int i = 0; i < 4; i++) {
      int idx = tid + i * 256;
      int r = idx >> 5, c = idx & 31;
      As[r][c] = A[(size_t)(bm + r) * K + k0 + c];
      Bs[r][c] = Bm[(size_t)(bn + r) * K + k0 + c];
    }
    __syncthreads();
#pragma unroll
    for (int kk = 0; kk < 32; kk++) {
      float b = Bs[tr][kk];
#pragma unroll
      for (int i = 0; i < 4; i++) acc[i] += As[tq * 4 + i][kk] * b;
    }
    __syncthreads();
  }
#pragma unroll
  for (int i = 0; i < 4; i++)
    C[(size_t)(bm + tq * 4 + i) * N + bn + tr] = acc[i] + bias[bn + tr];
}

// ---------------- K4: f32 NN gemm + bf16 hi/lo split output ----------------
__global__ __launch_bounds__(256) void k_gemm_f32_nn_split(
    const float* __restrict__ A, const float* __restrict__ Bm,
    unsigned short* __restrict__ Chi, unsigned short* __restrict__ Clo,
    int M, int N, int K) {
  __shared__ float As[32][33], Bs[32][33];
  int tid = threadIdx.x;
  int bm = blockIdx.x * 32, bn = blockIdx.y * 32;
  int tr = tid & 31, tq = tid >> 5;
  float acc[4] = {0.f, 0.f, 0.f, 0.f};
  for (int k0 = 0; k0 < K; k0 += 32) {
#pragma unroll
    for (int i = 0; i < 4; i++) {
      int idx = tid + i * 256;
      int r = idx >> 5, c = idx & 31;
      As[r][c] = A[(size_t)(bm + r) * K + k0 + c];
      Bs[r][c] = Bm[(size_t)(k0 + r) * N + bn + c];
    }
    __syncthreads();
#pragma unroll
    for (int kk = 0; kk < 32; kk++) {
      float b = Bs[kk][tr];
#pragma unroll
      for (int i = 0; i < 4; i++) acc[i] += As[tq * 4 + i][kk] * b;
    }
    __syncthreads();
  }
#pragma unroll
  for (int i = 0; i < 4; i++) {
    float q = acc[i];
    unsigned short hb = f2bf(q);
    size_t o = (size_t)(bm + tq * 4 + i) * N + bn + tr;
    Chi[o] = hb;
    Clo[o] = f2bf(q - bf2f(hb));
  }
}

// ---------------- K6: 3-pass split-bf16 TN gemm -> scores [128][32768] ----------------
// Counted-vmcnt pipeline (T3/T4): 3 LDS bufs, loads for tile t+2 issued at step
// t, vmcnt(6) before raw s_barrier (never drains to 0). 512 blocks, full K.
__global__ __launch_bounds__(256, 2) void k_gemm_scores(
    const unsigned short* __restrict__ Ah, const unsigned short* __restrict__ Al,
    const float* __restrict__ img, float* __restrict__ S) {
  // per buf (24 KB): A-hi @0 (8K), A-lo @8192, B-hi @16384 (4K), B-lo @20480
  __shared__ __attribute__((aligned(16))) char lds[73728];
  int tid = threadIdx.x, l = tid & 63, w = tid >> 6;
  int wm = w >> 1, wn = w & 1;              // 2 x 2 waves over 128x64 tile
  int bid = blockIdx.x;
  int xcd = bid & 7, local = bid >> 3;      // 64 N-tiles per XCD, contiguous
  int bn = (xcd * 64 + local) * 64;
  int lr = l & 15, lk8 = l >> 4;
  int sF = (lr >> 1) & 3;
  int srow = tid >> 2;
  int bswz = (tid & 3) ^ ((tid >> 3) & 3);
  const unsigned short* a0h = Ah + (size_t)srow * 1024 + bswz * 8;
  const unsigned short* a1h = Ah + (size_t)(64 + srow) * 1024 + bswz * 8;
  const unsigned short* a0l = Al + (size_t)srow * 1024 + bswz * 8;
  const unsigned short* a1l = Al + (size_t)(64 + srow) * 1024 + bswz * 8;
  const float* gB = img + (size_t)(bn + srow) * 1024 + (tid & 3) * 8;
  int bByte = srow * 64 + (bswz << 4);
  char* cur = &lds[0];
  char* nxt = &lds[24576];
  char* nx2 = &lds[49152];
  f32x4 vA0, vA1, vB0, vB1;
  f32x4 acc[4][2] = {};

#define SC_CONV(DST, V0, V1) { \
    s16x8 h_, lw_; \
    _Pragma("unroll") \
    for (int j = 0; j < 4; j++) { \
      unsigned short hb = f2bf((V0)[j]); \
      h_[j] = (short)hb; lw_[j] = (short)f2bf((V0)[j] - bf2f(hb)); \
      unsigned short hb1 = f2bf((V1)[j]); \
      h_[j + 4] = (short)hb1; lw_[j + 4] = (short)f2bf((V1)[j] - bf2f(hb1)); \
    } \
    *(s16x8*)((DST) + 16384 + bByte) = h_; \
    *(s16x8*)((DST) + 20480 + bByte) = lw_; }

#define SC_STEP(T, CI0, CI1, CO0, CO1) { \
    int kn = (((T) + 2 < 32) ? (T) + 2 : 31) * 32; \
    CO0 = *(const f32x4*)(gB + kn); \
    CO1 = *(const f32x4*)(gB + kn + 4); \
    SFENCE(); \
    gload_lds16(a0h + kn, nx2 + w * 1024); \
    gload_lds16(a1h + kn, nx2 + 4096 + w * 1024); \
    gload_lds16(a0l + kn, nx2 + 8192 + w * 1024); \
    gload_lds16(a1l + kn, nx2 + 12288 + w * 1024); \
    SFENCE(); \
    s16x8 ah[4], al4[4], bh[2], bl[2]; \
    _Pragma("unroll") \
    for (int i = 0; i < 4; i++) { \
      int byte = (wm * 64 + i * 16 + lr) * 64 + ((lk8 ^ sF) << 4); \
      ah[i] = *(const s16x8*)(cur + byte); \
      al4[i] = *(const s16x8*)(cur + 8192 + byte); \
    } \
    _Pragma("unroll") \
    for (int j = 0; j < 2; j++) { \
      int byte = (wn * 32 + j * 16 + lr) * 64 + ((lk8 ^ sF) << 4); \
      bh[j] = *(const s16x8*)(cur + 16384 + byte); \
      bl[j] = *(const s16x8*)(cur + 20480 + byte); \
    } \
    __builtin_amdgcn_s_setprio(1); \
    _Pragma("unroll") \
    for (int i = 0; i < 4; i++) \
      _Pragma("unroll") \
      for (int j = 0; j < 2; j++) { \
        acc[i][j] = __builtin_amdgcn_mfma_f32_16x16x32_bf16(ah[i], bh[j], acc[i][j], 0, 0, 0); \
        acc[i][j] = __builtin_amdgcn_mfma_f32_16x16x32_bf16(ah[i], bl[j], acc[i][j], 0, 0, 0); \
        acc[i][j] = __builtin_amdgcn_mfma_f32_16x16x32_bf16(al4[i], bh[j], acc[i][j], 0, 0, 0); \
      } \
    __builtin_amdgcn_s_setprio(0); \
    SC_CONV(nxt, CI0, CI1); \
    VMCNT(6); \
    LGKM0(); \
    SBAR(); \
    SFENCE(); \
    { char* t_ = cur; cur = nxt; nxt = nx2; nx2 = t_; } }

  // prologue: stage tiles 0 (buf0) and 1 (buf1); convert B(0); barrier
  vA0 = *(const f32x4*)(gB);
  vA1 = *(const f32x4*)(gB + 4);
  SFENCE();
  gload_lds16(a0h, cur + w * 1024);
  gload_lds16(a1h, cur + 4096 + w * 1024);
  gload_lds16(a0l, cur + 8192 + w * 1024);
  gload_lds16(a1l, cur + 12288 + w * 1024);
  SFENCE();
  vB0 = *(const f32x4*)(gB + 32);
  vB1 = *(const f32x4*)(gB + 36);
  SFENCE();
  gload_lds16(a0h + 32, nxt + w * 1024);
  gload_lds16(a1h + 32, nxt + 4096 + w * 1024);
  gload_lds16(a0l + 32, nxt + 8192 + w * 1024);
  gload_lds16(a1l + 32, nxt + 12288 + w * 1024);
  SFENCE();
  SC_CONV(cur, vA0, vA1);
  VMCNT(6);
  LGKM0();
  SBAR();
  SFENCE();

#pragma unroll 1
  for (int it = 0; it < 16; ++it) {
    SC_STEP(2 * it,     vB0, vB1, vA0, vA1);
    SC_STEP(2 * it + 1, vA0, vA1, vB0, vB1);
  }

  int rh = (l >> 4) * 4;
#pragma unroll
  for (int i = 0; i < 4; i++)
#pragma unroll
    for (int q = 0; q < 4; q++) {
      int gm = wm * 64 + i * 16 + rh + q;
#pragma unroll
      for (int j = 0; j < 2; j++) {
        int gn = bn + wn * 32 + j * 16 + lr;
        S[(size_t)gm * 32768 + gn] = acc[i][j][q];
      }
    }
#undef SC_STEP
#undef SC_CONV
}

// ---------------- K7: softmax over r (256), *1/32, f32 -> bf16 [b][l][r] ----------------
__global__ __launch_bounds__(256) void k_softmax(
    const float* __restrict__ S, unsigned short* __restrict__ P) {
  int w = threadIdx.x >> 6, l = threadIdx.x & 63;
  int row = blockIdx.x * 4 + w;            // row = l*128 + b, 16384 rows
  f32x4 x = ((const f32x4*)(S + (size_t)row * 256))[l];
  float m = fmaxf(fmaxf(x[0], x[1]), fmaxf(x[2], x[3]));
#pragma unroll
  for (int s = 1; s < 64; s <<= 1) m = fmaxf(m, __shfl_xor(m, s, 64));
  f32x4 e;
  float sum = 0.f;
#pragma unroll
  for (int j = 0; j < 4; j++) { e[j] = __expf(x[j] - m); sum += e[j]; }
#pragma unroll
  for (int s = 1; s < 64; s <<= 1) sum += __shfl_xor(sum, s, 64);
  float sc = 0.03125f / sum;
  s16x4 o;
#pragma unroll
  for (int j = 0; j < 4; j++) o[j] = (short)f2bf(e[j] * sc);
  int bb = row & 127, ll = row >> 7;
  ((s16x4*)(P + ((size_t)bb * 128 + ll) * 256))[l] = o;
}

// ---------------- K9: ctx[b][l][d] = sum_r attenB[b][l][r] * img[b][r][d] ----------------
// Counted-vmcnt pipeline; A async-staged, B reg-staged f32->bf16 transpose.
__global__ __launch_bounds__(256, 3) void k_gemm_ctx(
    const unsigned short* __restrict__ P, const float* __restrict__ img,
    unsigned short* __restrict__ Cp) {
  // per buf (16 KB): A @0 (8K), B @8192 (8K)
  __shared__ __attribute__((aligned(16))) char lds[49152];
  int tid = threadIdx.x, l = tid & 63, w = tid >> 6;
  int wm = w >> 1, wn = w & 1;
  int rid = blockIdx.x;
  int xcd = rid & 7, lid = rid >> 3;
  int b = xcd * 16 + (lid >> 3);
  int d0 = (lid & 7) * 128;
  const unsigned short* Pb = P + (size_t)b * 32768;
  int lr = l & 15, lk8 = l >> 4;
  int sF = (lr >> 1) & 3;
  int u = tid & 15, dc = tid >> 4;
  int srow = tid >> 2;
  int bswz = (tid & 3) ^ ((tid >> 3) & 3);
  const unsigned short* p0 = Pb + (size_t)srow * 256 + bswz * 8;
  const unsigned short* p1 = Pb + (size_t)(64 + srow) * 256 + bswz * 8;
  const float* gV = img + (size_t)(b * 256 + 2 * u) * 1024 + d0 + dc * 8;
  char* cur = &lds[0];
  char* nxt = &lds[16384];
  char* nx2 = &lds[32768];
  f32x4 vAa, vAb, vAc, vAd, vBa, vBb, vBc, vBd;
  f32x4 acc[4][4] = {};

#define CTX_CONV(DST, A0, A1, B0, B1) { \
    _Pragma("unroll") \
    for (int j = 0; j < 8; j++) { \
      float x0 = (j < 4) ? (A0)[j & 3] : (A1)[j & 3]; \
      float x1 = (j < 4) ? (B0)[j & 3] : (B1)[j & 3]; \
      int dd = dc * 8 + j; \
      unsigned int w32 = (unsigned int)f2bf(x0) | ((unsigned int)f2bf(x1) << 16); \
      int byte = 8192 + dd * 64 + ((4 * u) ^ (((dd >> 1) & 3) << 4)); \
      *(unsigned int*)((DST) + byte) = w32; \
    } }

#define CTX_STEP(T, CIa, CIb, CIc, CId, COa, COb, COc, COd) { \
    int kn = (((T) + 2 < 8) ? (T) + 2 : 7) * 32; \
    const float* gs = gV + (size_t)kn * 1024; \
    COa = *(const f32x4*)gs; \
    COb = *(const f32x4*)(gs + 4); \
    COc = *(const f32x4*)(gs + 1024); \
    COd = *(const f32x4*)(gs + 1028); \
    SFENCE(); \
    gload_lds16(p0 + kn, nx2 + w * 1024); \
    gload_lds16(p1 + kn, nx2 + 4096 + w * 1024); \
    SFENCE(); \
    s16x8 af[4], bf[4]; \
    _Pragma("unroll") \
    for (int i = 0; i < 4; i++) { \
      int byte = (wm * 64 + i * 16 + lr) * 64 + ((lk8 ^ sF) << 4); \
      af[i] = *(const s16x8*)(cur + byte); \
    } \
    _Pragma("unroll") \
    for (int j = 0; j < 4; j++) { \
      int n = wn * 64 + j * 16 + lr; \
      int byte = 8192 + n * 64 + ((lk8 ^ sF) << 4); \
      bf[j] = *(const s16x8*)(cur + byte); \
    } \
    __builtin_amdgcn_s_setprio(1); \
    _Pragma("unroll") \
    for (int i = 0; i < 4; i++) \
      _Pragma("unroll") \
      for (int j = 0; j < 4; j++) \
        acc[i][j] = __builtin_amdgcn_mfma_f32_16x16x32_bf16(af[i], bf[j], acc[i][j], 0, 0, 0); \
    __builtin_amdgcn_s_setprio(0); \
    CTX_CONV(nxt, CIa, CIb, CIc, CId); \
    VMCNT(6); \
    LGKM0(); \
    SBAR(); \
    SFENCE(); \
    { char* t_ = cur; cur = nxt; nxt = nx2; nx2 = t_; } }

  // prologue: stage tiles 0,1
  vAa = *(const f32x4*)gV;
  vAb = *(const f32x4*)(gV + 4);
  vAc = *(const f32x4*)(gV + 1024);
  vAd = *(const f32x4*)(gV + 1028);
  SFENCE();
  gload_lds16(p0, cur + w * 1024);
  gload_lds16(p1, cur + 4096 + w * 1024);
  SFENCE();
  {
    const float* gs = gV + 32 * 1024;
    vBa = *(const f32x4*)gs;
    vBb = *(const f32x4*)(gs + 4);
    vBc = *(const f32x4*)(gs + 1024);
    vBd = *(const f32x4*)(gs + 1028);
  }
  SFENCE();
  gload_lds16(p0 + 32, nxt + w * 1024);
  gload_lds16(p1 + 32, nxt + 4096 + w * 1024);
  SFENCE();
  CTX_CONV(cur, vAa, vAb, vAc, vAd);
  VMCNT(6);
  LGKM0();
  SBAR();
  SFENCE();

#pragma unroll 1
  for (int it = 0; it < 4; ++it) {
    CTX_STEP(2 * it,     vBa, vBb, vBc, vBd, vAa, vAb, vAc, vAd);
    CTX_STEP(2 * it + 1, vAa, vAb, vAc, vAd, vBa, vBb, vBc, vBd);
  }

  int rh = (l >> 4) * 4;
#pragma unroll
  for (int i = 0; i < 4; i++)
#pragma unroll
    for (int q = 0; q < 4; q++) {
      int gm = wm * 64 + i * 16 + rh + q;
#pragma unroll
      for (int j = 0; j < 4; j++) {
        int gn = wn * 64 + j * 16 + lr;
        Cp[((size_t)b * 128 + gm) * 1024 + d0 + gn] = f2bf(acc[i][j][q]);
      }
    }
#undef CTX_STEP
#undef CTX_CONV
}

// ---------------- K10: out[m][n] = sum_k ctx[m][k]*Wv[n][k] + bv[n]/32 ----------------
// Counted-vmcnt pipeline, both operands via gload_lds. M=16384, N=1024, K=1024.
__global__ __launch_bounds__(256, 3) void k_gemm_out(
    const unsigned short* __restrict__ A, const unsigned short* __restrict__ Bm,
    const float* __restrict__ bv, float* __restrict__ Out) {
  // per buf (16 KB): A @0 (8K), B @8192 (8K)
  __shared__ __attribute__((aligned(16))) char lds[49152];
  int tid = threadIdx.x, l = tid & 63, w = tid >> 6;
  int wm = w >> 1, wn = w & 1;
  int rid = blockIdx.x;
  int xcd = rid & 7, lid = rid >> 3;
  int bm = (xcd * 16 + (lid >> 3)) * 128;
  int bn = (lid & 7) * 128;
  int lr = l & 15, lk8 = l >> 4;
  int sF = (lr >> 1) & 3;
  int srow = tid >> 2;
  int swz = (tid & 3) ^ ((tid >> 3) & 3);
  const unsigned short* a0 = A + (size_t)(bm + srow) * 1024 + swz * 8;
  const unsigned short* a1 = A + (size_t)(bm + 64 + srow) * 1024 + swz * 8;
  const unsigned short* b0 = Bm + (size_t)(bn + srow) * 1024 + swz * 8;
  const unsigned short* b1 = Bm + (size_t)(bn + 64 + srow) * 1024 + swz * 8;
  char* cur = &lds[0];
  char* nxt = &lds[16384];
  char* nx2 = &lds[32768];
  f32x4 acc[4][4] = {};

#define OUT_STEP(T) { \
    int kn = (((T) + 2 < 32) ? (T) + 2 : 31) * 32; \
    gload_lds16(a0 + kn, nx2 + w * 1024); \
    gload_lds16(a1 + kn, nx2 + 4096 + w * 1024); \
    gload_lds16(b0 + kn, nx2 + 8192 + w * 1024); \
    gload_lds16(b1 + kn, nx2 + 12288 + w * 1024); \
    SFENCE(); \
    s16x8 af[4], bf[4]; \
    _Pragma("unroll") \
    for (int i = 0; i < 4; i++) { \
      int byte = (wm * 64 + i * 16 + lr) * 64 + ((lk8 ^ sF) << 4); \
      af[i] = *(const s16x8*)(cur + byte); \
    } \
    _Pragma("unroll") \
    for (int i = 0; i < 4; i++) { \
      int byte = 8192 + (wn * 64 + i * 16 + lr) * 64 + ((lk8 ^ sF) << 4); \
      bf[i] = *(const s16x8*)(cur + byte); \
    } \
    __builtin_amdgcn_s_setprio(1); \
    _Pragma("unroll") \
    for (int i = 0; i < 4; i++) \
      _Pragma("unroll") \
      for (int j = 0; j < 4; j++) \
        acc[i][j] = __builtin_amdgcn_mfma_f32_16x16x32_bf16(af[i], bf[j], acc[i][j], 0, 0, 0); \
    __builtin_amdgcn_s_setprio(0); \
    VMCNT(4); \
    SBAR(); \
    SFENCE(); \
    { char* t_ = cur; cur = nxt; nxt = nx2; nx2 = t_; } }

  // prologue: stage tiles 0,1
  gload_lds16(a0, cur + w * 1024);
  gload_lds16(a1, cur + 4096 + w * 1024);
  gload_lds16(b0, cur + 8192 + w * 1024);
  gload_lds16(b1, cur + 12288 + w * 1024);
  SFENCE();
  gload_lds16(a0 + 32, nxt + w * 1024);
  gload_lds16(a1 + 32, nxt + 4096 + w * 1024);
  gload_lds16(b0 + 32, nxt + 8192 + w * 1024);
  gload_lds16(b1 + 32, nxt + 12288 + w * 1024);
  SFENCE();
  VMCNT(4);
  SBAR();
  SFENCE();

#pragma unroll 1
  for (int t = 0; t < 32; ++t) {
    OUT_STEP(t);
  }

  int rh = (l >> 4) * 4;
#pragma unroll
  for (int i = 0; i < 4; i++)
#pragma unroll
    for (int q = 0; q < 4; q++) {
      int gm = bm + wm * 64 + i * 16 + rh + q;
#pragma unroll
      for (int j = 0; j < 4; j++) {
        int gn = bn + wn * 64 + j * 16 + lr;
        Out[(size_t)gm * 1024 + gn] = acc[i][j][q] + 0.03125f * bv[gn];
      }
    }
#undef OUT_STEP
}

extern "C" void kernel_launch(void* const* d_in, const int* in_sizes, int n_in,
                              void* d_out, int out_size, void* d_ws, size_t ws_size,
                              hipStream_t stream) {
  const float* cap = (const float*)d_in[0];
  const float* img = (const float*)d_in[1];
  const float* Wq  = (const float*)d_in[2];
  const float* bq  = (const float*)d_in[3];
  const float* Wk  = (const float*)d_in[4];
  // d_in[5] = bk: constant across r -> cancels in softmax. Unused.
  const float* Wv  = (const float*)d_in[6];
  const float* bv  = (const float*)d_in[7];
  float* out = (float*)d_out;

  char* ws = (char*)d_ws;
  if (ws_size < 61865984ull) return;  // fail loudly (output stays poisoned)
  float*          scores = (float*)(ws);                     // 16 MB
  unsigned short* atten  = (unsigned short*)(ws + 16777216); //  8 MB
  unsigned short* ctx    = (unsigned short*)(ws + 25165824); // 32 MB
  float*          Qb     = (float*)(ws + 58720256);          // 512 KB
  unsigned short* QWh    = (unsigned short*)(ws + 59244544); // 256 KB
  unsigned short* QWl    = (unsigned short*)(ws + 59506688); // 256 KB
  unsigned short* Wvh    = (unsigned short*)(ws + 59768832); //   2 MB

  k_convert_hi<<<1024, 256, 0, stream>>>(Wv, Wvh, 1048576 / 4);
  // Q = cap @ Wq^T + bq  (f32)
  k_gemm_f32_tn<<<dim3(4, 32), 256, 0, stream>>>(cap, Wq, bq, Qb, 128, 1024, 1024);
  // QW = Q @ Wk  (f32 -> bf16 hi/lo)
  k_gemm_f32_nn_split<<<dim3(4, 32), 256, 0, stream>>>(Qb, Wk, QWh, QWl, 128, 1024, 1024);
  // scores = QW @ img^T  (3-pass split bf16, counted-vmcnt pipeline)
  k_gemm_scores<<<512, 256, 0, stream>>>(QWh, QWl, img, scores);
  // atten[b][l][r] = softmax(scores) / 32  (bf16)
  k_softmax<<<4096, 256, 0, stream>>>(scores, atten);
  // ctx[b][l][d] = atten[b] @ img[b]  (bf16, counted-vmcnt pipeline)
  k_gemm_ctx<<<1024, 256, 0, stream>>>(atten, img, ctx);
  // out = ctx @ Wv^T + bv/32  (counted-vmcnt pipeline)
  k_gemm_out<<<1024, 256, 0, stream>>>(ctx, Wvh, bv, out);
}

// Round 9
// 214.953 us; speedup vs baseline: 1.1141x; 1.0041x over previous
//
#include <hip/hip_runtime.h>
#include <stdint.h>

typedef __attribute__((ext_vector_type(4))) float  f32x4;
typedef __attribute__((ext_vector_type(8))) short  s16x8;
typedef __attribute__((ext_vector_type(4))) short  s16x4;
typedef __attribute__((ext_vector_type(4))) unsigned int u32x4;
typedef __attribute__((ext_vector_type(2))) unsigned int u32x2;

__device__ __forceinline__ unsigned short f2bf(float x) {
  union { float f; unsigned int u; } a; a.f = x;
  unsigned int lsb = (a.u >> 16) & 1u;
  a.u += 0x7fffu + lsb;                    // round-to-nearest-even
  return (unsigned short)(a.u >> 16);
}
__device__ __forceinline__ float bf2f(unsigned short h) {
  union { unsigned int u; float f; } a; a.u = ((unsigned int)h) << 16; return a.f;
}

// HW packed f32->bf16 RNE: lo16 = bf16(a), hi16 = bf16(b). Bit-identical to f2bf.
__device__ __forceinline__ unsigned int cvtpk(float a, float b) {
  unsigned int d;
  asm("v_cvt_pk_bf16_f32 %0, %1, %2" : "=v"(d) : "v"(a), "v"(b));
  return d;
}
__device__ __forceinline__ float bflo_f(unsigned int u) {  // low bf16 as f32
  union { unsigned int u; float f; } x; x.u = u << 16; return x.f;
}
__device__ __forceinline__ float bfhi_f(unsigned int u) {  // high bf16 as f32
  union { unsigned int u; float f; } x; x.u = u & 0xffff0000u; return x.f;
}

// async global->LDS, 16B per lane. LDS dest must be wave-uniform base (+lane*16).
__device__ __forceinline__ void gload_lds16(const void* g, void* s) {
  __builtin_amdgcn_global_load_lds(
      (__attribute__((address_space(1))) void*)g,
      (__attribute__((address_space(3))) void*)s, 16, 0, 0);
}

#define VMCNT(N) asm volatile("s_waitcnt vmcnt(" #N ")" ::: "memory")
#define LGKM0()  asm volatile("s_waitcnt lgkmcnt(0)" ::: "memory")
#define SBAR()   __builtin_amdgcn_s_barrier()
#define SFENCE() __builtin_amdgcn_sched_barrier(0)

// ---------------- K2: f32 -> bf16 (hi only) ----------------
__global__ __launch_bounds__(256) void k_convert_hi(
    const float* __restrict__ in, unsigned short* __restrict__ out, int n4) {
  int i = blockIdx.x * 256 + threadIdx.x;
  if (i < n4) {
    f32x4 v = ((const f32x4*)in)[i];
    u32x2 h;
    h[0] = cvtpk(v[0], v[1]);
    h[1] = cvtpk(v[2], v[3]);
    ((u32x2*)out)[i] = h;
  }
}

// ---------------- K3: f32 TN gemm: C[m][n] = sum_k A[m][k]*B[n][k] + bias[n] ----------------
__global__ __launch_bounds__(256) void k_gemm_f32_tn(
    const float* __restrict__ A, const float* __restrict__ Bm,
    const float* __restrict__ bias, float* __restrict__ C,
    int M, int N, int K) {
  __shared__ float As[32][33], Bs[32][33];
  int tid = threadIdx.x;
  int bm = blockIdx.x * 32, bn = blockIdx.y * 32;
  int tr = tid & 31, tq = tid >> 5;
  float acc[4] = {0.f, 0.f, 0.f, 0.f};
  for (int k0 = 0; k0 < K; k0 += 32) {
#pragma unroll
    for (int i = 0; i < 4; i++) {
      int idx = tid + i * 256;
      int r = idx >> 5, c = idx & 31;
      As[r][c] = A[(size_t)(bm + r) * K + k0 + c];
      Bs[r][c] = Bm[(size_t)(bn + r) * K + k0 + c];
    }
    __syncthreads();
#pragma unroll
    for (int kk = 0; kk < 32; kk++) {
      float b = Bs[tr][kk];
#pragma unroll
      for (int i = 0; i < 4; i++) acc[i] += As[tq * 4 + i][kk] * b;
    }
    __syncthreads();
  }
#pragma unroll
  for (int i = 0; i < 4; i++)
    C[(size_t)(bm + tq * 4 + i) * N + bn + tr] = acc[i] + bias[bn + tr];
}

// ---------------- K4: f32 NN gemm + bf16 hi/lo split output ----------------
__global__ __launch_bounds__(256) void k_gemm_f32_nn_split(
    const float* __restrict__ A, const float* __restrict__ Bm,
    unsigned short* __restrict__ Chi, unsigned short* __restrict__ Clo,
    int M, int N, int K) {
  __shared__ float As[32][33], Bs[32][33];
  int tid = threadIdx.x;
  int bm = blockIdx.x * 32, bn = blockIdx.y * 32;
  int tr = tid & 31, tq = tid >> 5;
  float acc[4] = {0.f, 0.f, 0.f, 0.f};
  for (int k0 = 0; k0 < K; k0 += 32) {
#pragma unroll
    for (int i = 0; i < 4; i++) {
      int idx = tid + i * 256;
      int r = idx >> 5, c = idx & 31;
      As[r][c] = A[(size_t)(bm + r) * K + k0 + c];
      Bs[r][c] = Bm[(size_t)(k0 + r) * N + bn + c];
    }
    __syncthreads();
#pragma unroll
    for (int kk = 0; kk < 32; kk++) {
      float b = Bs[kk][tr];
#pragma unroll
      for (int i = 0; i < 4; i++) acc[i] += As[tq * 4 + i][kk] * b;
    }
    __syncthreads();
  }
#pragma unroll
  for (int i = 0; i < 4; i++) {
    float q = acc[i];
    unsigned short hb = f2bf(q);
    size_t o = (size_t)(bm + tq * 4 + i) * N + bn + tr;
    Chi[o] = hb;
    Clo[o] = f2bf(q - bf2f(hb));
  }
}

// ---------------- K6: 3-pass split-bf16 TN gemm -> scores [128][32768] ----------------
// Counted-vmcnt pipeline (T3/T4): 3 LDS bufs, loads for tile t+2 issued at step
// t, vmcnt(6) before raw s_barrier (never drains to 0). 512 blocks, full K.
__global__ __launch_bounds__(256, 2) void k_gemm_scores(
    const unsigned short* __restrict__ Ah, const unsigned short* __restrict__ Al,
    const float* __restrict__ img, float* __restrict__ S) {
  // per buf (24 KB): A-hi @0 (8K), A-lo @8192, B-hi @16384 (4K), B-lo @20480
  __shared__ __attribute__((aligned(16))) char lds[73728];
  int tid = threadIdx.x, l = tid & 63, w = tid >> 6;
  int wm = w >> 1, wn = w & 1;              // 2 x 2 waves over 128x64 tile
  int bid = blockIdx.x;
  int xcd = bid & 7, local = bid >> 3;      // 64 N-tiles per XCD, contiguous
  int bn = (xcd * 64 + local) * 64;
  int lr = l & 15, lk8 = l >> 4;
  int sF = (lr >> 1) & 3;
  int srow = tid >> 2;
  int bswz = (tid & 3) ^ ((tid >> 3) & 3);
  const unsigned short* a0h = Ah + (size_t)srow * 1024 + bswz * 8;
  const unsigned short* a1h = Ah + (size_t)(64 + srow) * 1024 + bswz * 8;
  const unsigned short* a0l = Al + (size_t)srow * 1024 + bswz * 8;
  const unsigned short* a1l = Al + (size_t)(64 + srow) * 1024 + bswz * 8;
  const float* gB = img + (size_t)(bn + srow) * 1024 + (tid & 3) * 8;
  int bByte = srow * 64 + (bswz << 4);
  char* cur = &lds[0];
  char* nxt = &lds[24576];
  char* nx2 = &lds[49152];
  f32x4 vA0, vA1, vB0, vB1;
  f32x4 acc[4][2] = {};

#define SC_CONV(DST, V0, V1) { \
    unsigned int h0 = cvtpk((V0)[0], (V0)[1]); \
    unsigned int h1 = cvtpk((V0)[2], (V0)[3]); \
    unsigned int h2 = cvtpk((V1)[0], (V1)[1]); \
    unsigned int h3 = cvtpk((V1)[2], (V1)[3]); \
    unsigned int l0 = cvtpk((V0)[0] - bflo_f(h0), (V0)[1] - bfhi_f(h0)); \
    unsigned int l1 = cvtpk((V0)[2] - bflo_f(h1), (V0)[3] - bfhi_f(h1)); \
    unsigned int l2 = cvtpk((V1)[0] - bflo_f(h2), (V1)[1] - bfhi_f(h2)); \
    unsigned int l3 = cvtpk((V1)[2] - bflo_f(h3), (V1)[3] - bfhi_f(h3)); \
    u32x4 hv = {h0, h1, h2, h3}, lv = {l0, l1, l2, l3}; \
    *(u32x4*)((DST) + 16384 + bByte) = hv; \
    *(u32x4*)((DST) + 20480 + bByte) = lv; }

#define SC_STEP(T, CI0, CI1, CO0, CO1) { \
    int kn = (((T) + 2 < 32) ? (T) + 2 : 31) * 32; \
    CO0 = *(const f32x4*)(gB + kn); \
    CO1 = *(const f32x4*)(gB + kn + 4); \
    SFENCE(); \
    gload_lds16(a0h + kn, nx2 + w * 1024); \
    gload_lds16(a1h + kn, nx2 + 4096 + w * 1024); \
    gload_lds16(a0l + kn, nx2 + 8192 + w * 1024); \
    gload_lds16(a1l + kn, nx2 + 12288 + w * 1024); \
    SFENCE(); \
    s16x8 ah[4], al4[4], bh[2], bl[2]; \
    _Pragma("unroll") \
    for (int i = 0; i < 4; i++) { \
      int byte = (wm * 64 + i * 16 + lr) * 64 + ((lk8 ^ sF) << 4); \
      ah[i] = *(const s16x8*)(cur + byte); \
      al4[i] = *(const s16x8*)(cur + 8192 + byte); \
    } \
    _Pragma("unroll") \
    for (int j = 0; j < 2; j++) { \
      int byte = (wn * 32 + j * 16 + lr) * 64 + ((lk8 ^ sF) << 4); \
      bh[j] = *(const s16x8*)(cur + 16384 + byte); \
      bl[j] = *(const s16x8*)(cur + 20480 + byte); \
    } \
    __builtin_amdgcn_s_setprio(1); \
    _Pragma("unroll") \
    for (int i = 0; i < 4; i++) \
      _Pragma("unroll") \
      for (int j = 0; j < 2; j++) { \
        acc[i][j] = __builtin_amdgcn_mfma_f32_16x16x32_bf16(ah[i], bh[j], acc[i][j], 0, 0, 0); \
        acc[i][j] = __builtin_amdgcn_mfma_f32_16x16x32_bf16(ah[i], bl[j], acc[i][j], 0, 0, 0); \
        acc[i][j] = __builtin_amdgcn_mfma_f32_16x16x32_bf16(al4[i], bh[j], acc[i][j], 0, 0, 0); \
      } \
    __builtin_amdgcn_s_setprio(0); \
    SC_CONV(nxt, CI0, CI1); \
    VMCNT(6); \
    LGKM0(); \
    SBAR(); \
    SFENCE(); \
    { char* t_ = cur; cur = nxt; nxt = nx2; nx2 = t_; } }

  // prologue: stage tiles 0 (buf0) and 1 (buf1); convert B(0); barrier
  vA0 = *(const f32x4*)(gB);
  vA1 = *(const f32x4*)(gB + 4);
  SFENCE();
  gload_lds16(a0h, cur + w * 1024);
  gload_lds16(a1h, cur + 4096 + w * 1024);
  gload_lds16(a0l, cur + 8192 + w * 1024);
  gload_lds16(a1l, cur + 12288 + w * 1024);
  SFENCE();
  vB0 = *(const f32x4*)(gB + 32);
  vB1 = *(const f32x4*)(gB + 36);
  SFENCE();
  gload_lds16(a0h + 32, nxt + w * 1024);
  gload_lds16(a1h + 32, nxt + 4096 + w * 1024);
  gload_lds16(a0l + 32, nxt + 8192 + w * 1024);
  gload_lds16(a1l + 32, nxt + 12288 + w * 1024);
  SFENCE();
  SC_CONV(cur, vA0, vA1);
  VMCNT(6);
  LGKM0();
  SBAR();
  SFENCE();

#pragma unroll 1
  for (int it = 0; it < 16; ++it) {
    SC_STEP(2 * it,     vB0, vB1, vA0, vA1);
    SC_STEP(2 * it + 1, vA0, vA1, vB0, vB1);
  }

  int rh = (l >> 4) * 4;
#pragma unroll
  for (int i = 0; i < 4; i++)
#pragma unroll
    for (int q = 0; q < 4; q++) {
      int gm = wm * 64 + i * 16 + rh + q;
#pragma unroll
      for (int j = 0; j < 2; j++) {
        int gn = bn + wn * 32 + j * 16 + lr;
        S[(size_t)gm * 32768 + gn] = acc[i][j][q];
      }
    }
#undef SC_STEP
#undef SC_CONV
}

// ---------------- K7: softmax over r (256), *1/32, f32 -> bf16 [b][l][r] ----------------
__global__ __launch_bounds__(256) void k_softmax(
    const float* __restrict__ S, unsigned short* __restrict__ P) {
  int w = threadIdx.x >> 6, l = threadIdx.x & 63;
  int row = blockIdx.x * 4 + w;            // row = l*128 + b, 16384 rows
  f32x4 x = ((const f32x4*)(S + (size_t)row * 256))[l];
  float m = fmaxf(fmaxf(x[0], x[1]), fmaxf(x[2], x[3]));
#pragma unroll
  for (int s = 1; s < 64; s <<= 1) m = fmaxf(m, __shfl_xor(m, s, 64));
  f32x4 e;
  float sum = 0.f;
#pragma unroll
  for (int j = 0; j < 4; j++) { e[j] = __expf(x[j] - m); sum += e[j]; }
#pragma unroll
  for (int s = 1; s < 64; s <<= 1) sum += __shfl_xor(sum, s, 64);
  float sc = 0.03125f / sum;
  u32x2 o;
  o[0] = cvtpk(e[0] * sc, e[1] * sc);
  o[1] = cvtpk(e[2] * sc, e[3] * sc);
  int bb = row & 127, ll = row >> 7;
  ((u32x2*)(P + ((size_t)bb * 128 + ll) * 256))[l] = o;
}

// ---------------- K9: ctx[b][l][d] = sum_r attenB[b][l][r] * img[b][r][d] ----------------
// Counted-vmcnt pipeline; A async-staged, B reg-staged f32->bf16 transpose.
__global__ __launch_bounds__(256, 3) void k_gemm_ctx(
    const unsigned short* __restrict__ P, const float* __restrict__ img,
    unsigned short* __restrict__ Cp) {
  // per buf (16 KB): A @0 (8K), B @8192 (8K)
  __shared__ __attribute__((aligned(16))) char lds[49152];
  int tid = threadIdx.x, l = tid & 63, w = tid >> 6;
  int wm = w >> 1, wn = w & 1;
  int rid = blockIdx.x;
  int xcd = rid & 7, lid = rid >> 3;
  int b = xcd * 16 + (lid >> 3);
  int d0 = (lid & 7) * 128;
  const unsigned short* Pb = P + (size_t)b * 32768;
  int lr = l & 15, lk8 = l >> 4;
  int sF = (lr >> 1) & 3;
  int u = tid & 15, dc = tid >> 4;
  int srow = tid >> 2;
  int bswz = (tid & 3) ^ ((tid >> 3) & 3);
  const unsigned short* p0 = Pb + (size_t)srow * 256 + bswz * 8;
  const unsigned short* p1 = Pb + (size_t)(64 + srow) * 256 + bswz * 8;
  const float* gV = img + (size_t)(b * 256 + 2 * u) * 1024 + d0 + dc * 8;
  char* cur = &lds[0];
  char* nxt = &lds[16384];
  char* nx2 = &lds[32768];
  f32x4 vAa, vAb, vAc, vAd, vBa, vBb, vBc, vBd;
  f32x4 acc[4][4] = {};

#define CTX_CONV(DST, A0, A1, B0, B1) { \
    _Pragma("unroll") \
    for (int j = 0; j < 8; j++) { \
      float x0 = (j < 4) ? (A0)[j & 3] : (A1)[j & 3]; \
      float x1 = (j < 4) ? (B0)[j & 3] : (B1)[j & 3]; \
      int dd = dc * 8 + j; \
      unsigned int w32 = cvtpk(x0, x1); \
      int byte = 8192 + dd * 64 + ((4 * u) ^ (((dd >> 1) & 3) << 4)); \
      *(unsigned int*)((DST) + byte) = w32; \
    } }

#define CTX_STEP(T, CIa, CIb, CIc, CId, COa, COb, COc, COd) { \
    int kn = (((T) + 2 < 8) ? (T) + 2 : 7) * 32; \
    const float* gs = gV + (size_t)kn * 1024; \
    COa = *(const f32x4*)gs; \
    COb = *(const f32x4*)(gs + 4); \
    COc = *(const f32x4*)(gs + 1024); \
    COd = *(const f32x4*)(gs + 1028); \
    SFENCE(); \
    gload_lds16(p0 + kn, nx2 + w * 1024); \
    gload_lds16(p1 + kn, nx2 + 4096 + w * 1024); \
    SFENCE(); \
    s16x8 af[4], bf[4]; \
    _Pragma("unroll") \
    for (int i = 0; i < 4; i++) { \
      int byte = (wm * 64 + i * 16 + lr) * 64 + ((lk8 ^ sF) << 4); \
      af[i] = *(const s16x8*)(cur + byte); \
    } \
    _Pragma("unroll") \
    for (int j = 0; j < 4; j++) { \
      int n = wn * 64 + j * 16 + lr; \
      int byte = 8192 + n * 64 + ((lk8 ^ sF) << 4); \
      bf[j] = *(const s16x8*)(cur + byte); \
    } \
    __builtin_amdgcn_s_setprio(1); \
    _Pragma("unroll") \
    for (int i = 0; i < 4; i++) \
      _Pragma("unroll") \
      for (int j = 0; j < 4; j++) \
        acc[i][j] = __builtin_amdgcn_mfma_f32_16x16x32_bf16(af[i], bf[j], acc[i][j], 0, 0, 0); \
    __builtin_amdgcn_s_setprio(0); \
    CTX_CONV(nxt, CIa, CIb, CIc, CId); \
    VMCNT(6); \
    LGKM0(); \
    SBAR(); \
    SFENCE(); \
    { char* t_ = cur; cur = nxt; nxt = nx2; nx2 = t_; } }

  // prologue: stage tiles 0,1
  vAa = *(const f32x4*)gV;
  vAb = *(const f32x4*)(gV + 4);
  vAc = *(const f32x4*)(gV + 1024);
  vAd = *(const f32x4*)(gV + 1028);
  SFENCE();
  gload_lds16(p0, cur + w * 1024);
  gload_lds16(p1, cur + 4096 + w * 1024);
  SFENCE();
  {
    const float* gs = gV + 32 * 1024;
    vBa = *(const f32x4*)gs;
    vBb = *(const f32x4*)(gs + 4);
    vBc = *(const f32x4*)(gs + 1024);
    vBd = *(const f32x4*)(gs + 1028);
  }
  SFENCE();
  gload_lds16(p0 + 32, nxt + w * 1024);
  gload_lds16(p1 + 32, nxt + 4096 + w * 1024);
  SFENCE();
  CTX_CONV(cur, vAa, vAb, vAc, vAd);
  VMCNT(6);
  LGKM0();
  SBAR();
  SFENCE();

#pragma unroll 1
  for (int it = 0; it < 4; ++it) {
    CTX_STEP(2 * it,     vBa, vBb, vBc, vBd, vAa, vAb, vAc, vAd);
    CTX_STEP(2 * it + 1, vAa, vAb, vAc, vAd, vBa, vBb, vBc, vBd);
  }

  int rh = (l >> 4) * 4;
#pragma unroll
  for (int i = 0; i < 4; i++)
#pragma unroll
    for (int q = 0; q < 4; q++) {
      int gm = wm * 64 + i * 16 + rh + q;
#pragma unroll
      for (int j = 0; j < 4; j++) {
        int gn = wn * 64 + j * 16 + lr;
        Cp[((size_t)b * 128 + gm) * 1024 + d0 + gn] = f2bf(acc[i][j][q]);
      }
    }
#undef CTX_STEP
#undef CTX_CONV
}

// ---------------- K10: out[m][n] = sum_k ctx[m][k]*Wv[n][k] + bv[n]/32 ----------------
// Counted-vmcnt pipeline, both operands via gload_lds. M=16384, N=1024, K=1024.
__global__ __launch_bounds__(256, 3) void k_gemm_out(
    const unsigned short* __restrict__ A, const unsigned short* __restrict__ Bm,
    const float* __restrict__ bv, float* __restrict__ Out) {
  // per buf (16 KB): A @0 (8K), B @8192 (8K)
  __shared__ __attribute__((aligned(16))) char lds[49152];
  int tid = threadIdx.x, l = tid & 63, w = tid >> 6;
  int wm = w >> 1, wn = w & 1;
  int rid = blockIdx.x;
  int xcd = rid & 7, lid = rid >> 3;
  int bm = (xcd * 16 + (lid >> 3)) * 128;
  int bn = (lid & 7) * 128;
  int lr = l & 15, lk8 = l >> 4;
  int sF = (lr >> 1) & 3;
  int srow = tid >> 2;
  int swz = (tid & 3) ^ ((tid >> 3) & 3);
  const unsigned short* a0 = A + (size_t)(bm + srow) * 1024 + swz * 8;
  const unsigned short* a1 = A + (size_t)(bm + 64 + srow) * 1024 + swz * 8;
  const unsigned short* b0 = Bm + (size_t)(bn + srow) * 1024 + swz * 8;
  const unsigned short* b1 = Bm + (size_t)(bn + 64 + srow) * 1024 + swz * 8;
  char* cur = &lds[0];
  char* nxt = &lds[16384];
  char* nx2 = &lds[32768];
  f32x4 acc[4][4] = {};

#define OUT_STEP(T) { \
    int kn = (((T) + 2 < 32) ? (T) + 2 : 31) * 32; \
    gload_lds16(a0 + kn, nx2 + w * 1024); \
    gload_lds16(a1 + kn, nx2 + 4096 + w * 1024); \
    gload_lds16(b0 + kn, nx2 + 8192 + w * 1024); \
    gload_lds16(b1 + kn, nx2 + 12288 + w * 1024); \
    SFENCE(); \
    s16x8 af[4], bf[4]; \
    _Pragma("unroll") \
    for (int i = 0; i < 4; i++) { \
      int byte = (wm * 64 + i * 16 + lr) * 64 + ((lk8 ^ sF) << 4); \
      af[i] = *(const s16x8*)(cur + byte); \
    } \
    _Pragma("unroll") \
    for (int i = 0; i < 4; i++) { \
      int byte = 8192 + (wn * 64 + i * 16 + lr) * 64 + ((lk8 ^ sF) << 4); \
      bf[i] = *(const s16x8*)(cur + byte); \
    } \
    __builtin_amdgcn_s_setprio(1); \
    _Pragma("unroll") \
    for (int i = 0; i < 4; i++) \
      _Pragma("unroll") \
      for (int j = 0; j < 4; j++) \
        acc[i][j] = __builtin_amdgcn_mfma_f32_16x16x32_bf16(af[i], bf[j], acc[i][j], 0, 0, 0); \
    __builtin_amdgcn_s_setprio(0); \
    VMCNT(4); \
    SBAR(); \
    SFENCE(); \
    { char* t_ = cur; cur = nxt; nxt = nx2; nx2 = t_; } }

  // prologue: stage tiles 0,1
  gload_lds16(a0, cur + w * 1024);
  gload_lds16(a1, cur + 4096 + w * 1024);
  gload_lds16(b0, cur + 8192 + w * 1024);
  gload_lds16(b1, cur + 12288 + w * 1024);
  SFENCE();
  gload_lds16(a0 + 32, nxt + w * 1024);
  gload_lds16(a1 + 32, nxt + 4096 + w * 1024);
  gload_lds16(b0 + 32, nxt + 8192 + w * 1024);
  gload_lds16(b1 + 32, nxt + 12288 + w * 1024);
  SFENCE();
  VMCNT(4);
  SBAR();
  SFENCE();

#pragma unroll 1
  for (int t = 0; t < 32; ++t) {
    OUT_STEP(t);
  }

  int rh = (l >> 4) * 4;
#pragma unroll
  for (int i = 0; i < 4; i++)
#pragma unroll
    for (int q = 0; q < 4; q++) {
      int gm = bm + wm * 64 + i * 16 + rh + q;
#pragma unroll
      for (int j = 0; j < 4; j++) {
        int gn = bn + wn * 64 + j * 16 + lr;
        Out[(size_t)gm * 1024 + gn] = acc[i][j][q] + 0.03125f * bv[gn];
      }
    }
#undef OUT_STEP
}

extern "C" void kernel_launch(void* const* d_in, const int* in_sizes, int n_in,
                              void* d_out, int out_size, void* d_ws, size_t ws_size,
                              hipStream_t stream) {
  const float* cap = (const float*)d_in[0];
  const float* img = (const float*)d_in[1];
  const float* Wq  = (const float*)d_in[2];
  const float* bq  = (const float*)d_in[3];
  const float* Wk  = (const float*)d_in[4];
  // d_in[5] = bk: constant across r -> cancels in softmax. Unused.
  const float* Wv  = (const float*)d_in[6];
  const float* bv  = (const float*)d_in[7];
  float* out = (float*)d_out;

  char* ws = (char*)d_ws;
  if (ws_size < 61865984ull) return;  // fail loudly (output stays poisoned)
  float*          scores = (float*)(ws);                     // 16 MB
  unsigned short* atten  = (unsigned short*)(ws + 16777216); //  8 MB
  unsigned short* ctx    = (unsigned short*)(ws + 25165824); // 32 MB
  float*          Qb     = (float*)(ws + 58720256);          // 512 KB
  unsigned short* QWh    = (unsigned short*)(ws + 59244544); // 256 KB
  unsigned short* QWl    = (unsigned short*)(ws + 59506688); // 256 KB
  unsigned short* Wvh    = (unsigned short*)(ws + 59768832); //   2 MB

  k_convert_hi<<<1024, 256, 0, stream>>>(Wv, Wvh, 1048576 / 4);
  // Q = cap @ Wq^T + bq  (f32)
  k_gemm_f32_tn<<<dim3(4, 32), 256, 0, stream>>>(cap, Wq, bq, Qb, 128, 1024, 1024);
  // QW = Q @ Wk  (f32 -> bf16 hi/lo)
  k_gemm_f32_nn_split<<<dim3(4, 32), 256, 0, stream>>>(Qb, Wk, QWh, QWl, 128, 1024, 1024);
  // scores = QW @ img^T  (3-pass split bf16, counted-vmcnt pipeline)
  k_gemm_scores<<<512, 256, 0, stream>>>(QWh, QWl, img, scores);
  // atten[b][l][r] = softmax(scores) / 32  (bf16)
  k_softmax<<<4096, 256, 0, stream>>>(scores, atten);
  // ctx[b][l][d] = atten[b] @ img[b]  (bf16, counted-vmcnt pipeline)
  k_gemm_ctx<<<1024, 256, 0, stream>>>(atten, img, ctx);
  // out = ctx @ Wv^T + bv/32  (counted-vmcnt pipeline)
  k_gemm_out<<<1024, 256, 0, stream>>>(ctx, Wvh, bv, out);
}

// Round 10
// 212.958 us; speedup vs baseline: 1.1245x; 1.0094x over previous
//
#include <hip/hip_runtime.h>
#include <stdint.h>

typedef __attribute__((ext_vector_type(4))) float  f32x4;
typedef __attribute__((ext_vector_type(8))) short  s16x8;
typedef __attribute__((ext_vector_type(4))) short  s16x4;
typedef __attribute__((ext_vector_type(4))) unsigned int u32x4;
typedef __attribute__((ext_vector_type(2))) unsigned int u32x2;

__device__ __forceinline__ unsigned short f2bf(float x) {
  union { float f; unsigned int u; } a; a.f = x;
  unsigned int lsb = (a.u >> 16) & 1u;
  a.u += 0x7fffu + lsb;                    // round-to-nearest-even
  return (unsigned short)(a.u >> 16);
}
__device__ __forceinline__ float bf2f(unsigned short h) {
  union { unsigned int u; float f; } a; a.u = ((unsigned int)h) << 16; return a.f;
}
// HW packed f32->bf16 RNE: lo16 = bf16(a), hi16 = bf16(b). Bit-identical to f2bf.
__device__ __forceinline__ unsigned int cvtpk(float a, float b) {
  unsigned int d;
  asm("v_cvt_pk_bf16_f32 %0, %1, %2" : "=v"(d) : "v"(a), "v"(b));
  return d;
}
__device__ __forceinline__ float bflo_f(unsigned int u) {
  union { unsigned int u; float f; } x; x.u = u << 16; return x.f;
}
__device__ __forceinline__ float bfhi_f(unsigned int u) {
  union { unsigned int u; float f; } x; x.u = u & 0xffff0000u; return x.f;
}
__device__ __forceinline__ s16x8 pk4(unsigned a, unsigned b, unsigned c, unsigned d) {
  union { u32x4 u; s16x8 s; } x;
  u32x4 v = {a, b, c, d}; x.u = v; return x.s;
}

__device__ __forceinline__ void gload_lds16(const void* g, void* s) {
  __builtin_amdgcn_global_load_lds(
      (__attribute__((address_space(1))) void*)g,
      (__attribute__((address_space(3))) void*)s, 16, 0, 0);
}

#define VMCNT(N) asm volatile("s_waitcnt vmcnt(" #N ")" ::: "memory")
#define LGKM0()  asm volatile("s_waitcnt lgkmcnt(0)" ::: "memory")
#define SBAR()   __builtin_amdgcn_s_barrier()
#define SFENCE() __builtin_amdgcn_sched_barrier(0)

// ---------------- K2: f32 -> bf16 (hi only) ----------------
__global__ __launch_bounds__(256) void k_convert_hi(
    const float* __restrict__ in, unsigned short* __restrict__ out, int n4) {
  int i = blockIdx.x * 256 + threadIdx.x;
  if (i < n4) {
    f32x4 v = ((const f32x4*)in)[i];
    u32x2 h;
    h[0] = cvtpk(v[0], v[1]);
    h[1] = cvtpk(v[2], v[3]);
    ((u32x2*)out)[i] = h;
  }
}

// ---------------- K3: f32 TN gemm: C[m][n] = sum_k A[m][k]*B[n][k] + bias[n] ----------------
__global__ __launch_bounds__(256) void k_gemm_f32_tn(
    const float* __restrict__ A, const float* __restrict__ Bm,
    const float* __restrict__ bias, float* __restrict__ C,
    int M, int N, int K) {
  __shared__ float As[32][33], Bs[32][33];
  int tid = threadIdx.x;
  int bm = blockIdx.x * 32, bn = blockIdx.y * 32;
  int tr = tid & 31, tq = tid >> 5;
  float acc[4] = {0.f, 0.f, 0.f, 0.f};
  for (int k0 = 0; k0 < K; k0 += 32) {
#pragma unroll
    for (int i = 0; i < 4; i++) {
      int idx = tid + i * 256;
      int r = idx >> 5, c = idx & 31;
      As[r][c] = A[(size_t)(bm + r) * K + k0 + c];
      Bs[r][c] = Bm[(size_t)(bn + r) * K + k0 + c];
    }
    __syncthreads();
#pragma unroll
    for (int kk = 0; kk < 32; kk++) {
      float b = Bs[tr][kk];
#pragma unroll
      for (int i = 0; i < 4; i++) acc[i] += As[tq * 4 + i][kk] * b;
    }
    __syncthreads();
  }
#pragma unroll
  for (int i = 0; i < 4; i++)
    C[(size_t)(bm + tq * 4 + i) * N + bn + tr] = acc[i] + bias[bn + tr];
}

// ---------------- K4: f32 NN gemm + bf16 hi/lo split output ----------------
__global__ __launch_bounds__(256) void k_gemm_f32_nn_split(
    const float* __restrict__ A, const float* __restrict__ Bm,
    unsigned short* __restrict__ Chi, unsigned short* __restrict__ Clo,
    int M, int N, int K) {
  __shared__ float As[32][33], Bs[32][33];
  int tid = threadIdx.x;
  int bm = blockIdx.x * 32, bn = blockIdx.y * 32;
  int tr = tid & 31, tq = tid >> 5;
  float acc[4] = {0.f, 0.f, 0.f, 0.f};
  for (int k0 = 0; k0 < K; k0 += 32) {
#pragma unroll
    for (int i = 0; i < 4; i++) {
      int idx = tid + i * 256;
      int r = idx >> 5, c = idx & 31;
      As[r][c] = A[(size_t)(bm + r) * K + k0 + c];
      Bs[r][c] = Bm[(size_t)(k0 + r) * N + bn + c];
    }
    __syncthreads();
#pragma unroll
    for (int kk = 0; kk < 32; kk++) {
      float b = Bs[kk][tr];
#pragma unroll
      for (int i = 0; i < 4; i++) acc[i] += As[tq * 4 + i][kk] * b;
    }
    __syncthreads();
  }
#pragma unroll
  for (int i = 0; i < 4; i++) {
    float q = acc[i];
    unsigned short hb = f2bf(q);
    size_t o = (size_t)(bm + tq * 4 + i) * N + bn + tr;
    Chi[o] = hb;
    Clo[o] = f2bf(q - bf2f(hb));
  }
}

// ---------------- K5: fused scores + softmax + ctx ----------------
// Block (b, lh): scores S[64 l][256 r] = QW[lh] @ img[b]^T (3-pass split bf16,
// K=1024, counted-vmcnt 3-buf); in-register softmax (row = l, over r=256);
// P -> swizzled LDS; ctx[b][lh*64..][0..1023] = P @ img[b] (transpose-staged).
// 512 threads = 8 waves (2x4 over 64x256).
__global__ __launch_bounds__(512, 2) void k_fused(
    const unsigned short* __restrict__ QWh, const unsigned short* __restrict__ QWl,
    const float* __restrict__ img, unsigned short* __restrict__ Cp) {
  // LDS map: scores bufs S0@0, S1@40960, S2@81920 (each 40 KB: Ah@0, Al@4096,
  // Bf32@8192..40960). After scores: P@81920 (32 KB), red@114688 (2 KB),
  // ctx B-bufs C0@0, C1@16384, C2@32768 (16 KB each).
  __shared__ __attribute__((aligned(16))) char lds[122880];
  int tid = threadIdx.x, l = tid & 63, w = tid >> 6;
  int wm = w >> 2, wn = w & 3;              // 2 x 4 wave grid
  int lr = l & 15, lk8 = l >> 4;
  int rh = lk8 * 4;
  int bid = blockIdx.x;
  int xcd = bid & 7, loc = bid >> 3;
  int b = xcd * 16 + (loc >> 1);
  int lh = loc & 1;
  const int Poff = 81920, RMAX = 114688, RSUM = 115712;

  // ---- scores staging setup ----
  int arow = (w & 3) * 16 + (l >> 2);
  int achk = (l & 3) ^ ((arow >> 1) & 3);
  const unsigned short* aW = (w < 4) ? QWh : QWl;
  const unsigned short* asrc = aW + (size_t)(lh * 64 + arow) * 1024 + achk * 8;
  int aOff = ((w < 4) ? 0 : 4096) + (w & 3) * 1024;
  int bchk = (l & 7) ^ (l >> 3);
  const float* bsrc0 = img + ((size_t)b * 256 + 0   + w * 8 + (l >> 3)) * 1024 + bchk * 4;
  const float* bsrc1 = img + ((size_t)b * 256 + 64  + w * 8 + (l >> 3)) * 1024 + bchk * 4;
  const float* bsrc2 = img + ((size_t)b * 256 + 128 + w * 8 + (l >> 3)) * 1024 + bchk * 4;
  const float* bsrc3 = img + ((size_t)b * 256 + 192 + w * 8 + (l >> 3)) * 1024 + bchk * 4;
  int bOff0 = 8192 + 0     + w * 1024;
  int bOff1 = 8192 + 8192  + w * 1024;
  int bOff2 = 8192 + 16384 + w * 1024;
  int bOff3 = 8192 + 24576 + w * 1024;

  char* scur = &lds[0];
  char* snxt = &lds[40960];
  char* snx2 = &lds[81920];
  f32x4 acc[2][4] = {};

#define SC_STAGE(T, BUF) { \
    gload_lds16(asrc + (T) * 32, (BUF) + aOff); \
    gload_lds16(bsrc0 + (T) * 32, (BUF) + bOff0); \
    gload_lds16(bsrc1 + (T) * 32, (BUF) + bOff1); \
    gload_lds16(bsrc2 + (T) * 32, (BUF) + bOff2); \
    gload_lds16(bsrc3 + (T) * 32, (BUF) + bOff3); }

#define SC_COMPUTE(BUF) { \
    s16x8 ah[2], al2[2], bh[4], bl[4]; \
    _Pragma("unroll") \
    for (int i = 0; i < 2; i++) { \
      int row = wm * 32 + i * 16 + lr; \
      int byte = row * 64 + ((lk8 ^ ((row >> 1) & 3)) << 4); \
      ah[i] = *(const s16x8*)((BUF) + byte); \
      al2[i] = *(const s16x8*)((BUF) + 4096 + byte); \
    } \
    _Pragma("unroll") \
    for (int j = 0; j < 4; j++) { \
      int n = wn * 64 + j * 16 + lr; \
      int c0 = (2 * lk8) ^ (lr & 7); \
      int c1 = (2 * lk8 + 1) ^ (lr & 7); \
      f32x4 v0 = *(const f32x4*)((BUF) + 8192 + n * 128 + c0 * 16); \
      f32x4 v1 = *(const f32x4*)((BUF) + 8192 + n * 128 + c1 * 16); \
      unsigned h0 = cvtpk(v0[0], v0[1]), h1 = cvtpk(v0[2], v0[3]); \
      unsigned h2 = cvtpk(v1[0], v1[1]), h3 = cvtpk(v1[2], v1[3]); \
      unsigned q0 = cvtpk(v0[0] - bflo_f(h0), v0[1] - bfhi_f(h0)); \
      unsigned q1 = cvtpk(v0[2] - bflo_f(h1), v0[3] - bfhi_f(h1)); \
      unsigned q2 = cvtpk(v1[0] - bflo_f(h2), v1[1] - bfhi_f(h2)); \
      unsigned q3 = cvtpk(v1[2] - bflo_f(h3), v1[3] - bfhi_f(h3)); \
      bh[j] = pk4(h0, h1, h2, h3); \
      bl[j] = pk4(q0, q1, q2, q3); \
    } \
    __builtin_amdgcn_s_setprio(1); \
    _Pragma("unroll") \
    for (int i = 0; i < 2; i++) \
      _Pragma("unroll") \
      for (int j = 0; j < 4; j++) { \
        acc[i][j] = __builtin_amdgcn_mfma_f32_16x16x32_bf16(ah[i], bh[j], acc[i][j], 0, 0, 0); \
        acc[i][j] = __builtin_amdgcn_mfma_f32_16x16x32_bf16(ah[i], bl[j], acc[i][j], 0, 0, 0); \
        acc[i][j] = __builtin_amdgcn_mfma_f32_16x16x32_bf16(al2[i], bh[j], acc[i][j], 0, 0, 0); \
      } \
    __builtin_amdgcn_s_setprio(0); }

  // prologue: stage tiles 0,1
  SC_STAGE(0, scur);
  SFENCE();
  SC_STAGE(1, snxt);
  SFENCE();
  VMCNT(5);
  SBAR();
  SFENCE();
#pragma unroll 1
  for (int t = 0; t < 30; ++t) {
    SC_STAGE(t + 2, snx2);
    SFENCE();
    SC_COMPUTE(scur);
    VMCNT(5);
    SBAR();
    SFENCE();
    { char* t_ = scur; scur = snxt; snxt = snx2; snx2 = t_; }
  }
  // epilogue steps 30,31 (no stage, drain)
  SC_COMPUTE(scur);
  VMCNT(0);
  SBAR();
  SFENCE();
  { char* t_ = scur; scur = snxt; snxt = snx2; snx2 = t_; }
  SC_COMPUTE(scur);
  SBAR();
  SFENCE();
#undef SC_STAGE
#undef SC_COMPUTE

  // ---- softmax over r=256 (rows = caption l), in-register + LDS reduce ----
  {
    // 1) per-wave row-max partials
#pragma unroll
    for (int i = 0; i < 2; i++)
#pragma unroll
      for (int q = 0; q < 4; q++) {
        float m = fmaxf(fmaxf(acc[i][0][q], acc[i][1][q]),
                        fmaxf(acc[i][2][q], acc[i][3][q]));
#pragma unroll
        for (int s = 1; s < 16; s <<= 1) m = fmaxf(m, __shfl_xor(m, s, 64));
        if (lr == 0)
          *(float*)(lds + RMAX + (wm * 32 + i * 16 + rh + q) * 16 + wn * 4) = m;
      }
    LGKM0();
    SBAR();
    // 2) global max -> exp -> per-wave sum partials
#pragma unroll
    for (int i = 0; i < 2; i++)
#pragma unroll
      for (int q = 0; q < 4; q++) {
        int row = wm * 32 + i * 16 + rh + q;
        const float* rm = (const float*)(lds + RMAX + row * 16);
        float g = fmaxf(fmaxf(rm[0], rm[1]), fmaxf(rm[2], rm[3]));
        float ps = 0.f;
#pragma unroll
        for (int j = 0; j < 4; j++) {
          float e = __expf(acc[i][j][q] - g);
          acc[i][j][q] = e;
          ps += e;
        }
#pragma unroll
        for (int s = 1; s < 16; s <<= 1) ps += __shfl_xor(ps, s, 64);
        if (lr == 0) *(float*)(lds + RSUM + row * 16 + wn * 4) = ps;
      }
    LGKM0();
    SBAR();
    // 3) scale by 1/(32*sum), write bf16 P to swizzled LDS [64][256]
#pragma unroll
    for (int i = 0; i < 2; i++)
#pragma unroll
      for (int q = 0; q < 4; q++) {
        int row = wm * 32 + i * 16 + rh + q;
        const float* rs = (const float*)(lds + RSUM + row * 16);
        float sc = 0.03125f / (rs[0] + rs[1] + rs[2] + rs[3]);
#pragma unroll
        for (int j = 0; j < 4; j++) {
          int col = wn * 64 + j * 16 + lr;
          int byte = Poff + row * 512 +
                     (((col >> 3) ^ ((row & 7) << 2)) << 4) + (col & 7) * 2;
          *(unsigned short*)(lds + byte) = f2bf(acc[i][j][q] * sc);
        }
      }
    LGKM0();
    SBAR();
    SFENCE();
  }

  // ---- ctx phase: ctx[64 l][1024 d] = P @ img[b], 32 steps (4 d-chunks x 8 k) ----
  {
    int u = tid & 15, dc = tid >> 4;        // u: r-pair, dc: 8-d group (0..31)
    const float* gva = img + ((size_t)b * 256 + 2 * u) * 1024 + dc * 8;
    const float* gvb = gva + 1024;
    char* ccur = &lds[0];
    char* cnxt = &lds[16384];
    char* cnx2 = &lds[32768];
    f32x4 vAa, vAb, vAc, vAd, vBa, vBb, vBc, vBd;
    f32x4 acc2[2][4] = {};

#define CTX_LOAD(T, Ra, Rb, Rc, Rd) { \
    int tt = ((T) < 32) ? (T) : 31; \
    size_t off = (size_t)((tt & 7) * 32) * 1024 + (tt >> 3) * 256; \
    Ra = *(const f32x4*)(gva + off); \
    Rb = *(const f32x4*)(gva + off + 4); \
    Rc = *(const f32x4*)(gvb + off); \
    Rd = *(const f32x4*)(gvb + off + 4); }

#define CTX_CONV(DST, Ra, Rb, Rc, Rd) { \
    _Pragma("unroll") \
    for (int j = 0; j < 8; j++) { \
      float x0 = (j < 4) ? (Ra)[j & 3] : (Rb)[j & 3]; \
      float x1 = (j < 4) ? (Rc)[j & 3] : (Rd)[j & 3]; \
      int dd = dc * 8 + j; \
      unsigned int w32 = cvtpk(x0, x1); \
      int byte = dd * 64 + ((4 * u) ^ (((dd >> 1) & 3) << 4)); \
      *(unsigned int*)((DST) + byte) = w32; \
    } }

#define CTX_STEP(T, CIa, CIb, CIc, CId, COa, COb, COc, COd) { \
    CTX_LOAD((T) + 2, COa, COb, COc, COd); \
    SFENCE(); \
    s16x8 af[2], bf[4]; \
    _Pragma("unroll") \
    for (int i = 0; i < 2; i++) { \
      int row = wm * 32 + i * 16 + lr; \
      int rc = ((T) & 7) * 4 + lk8; \
      int byte = Poff + row * 512 + ((rc ^ ((row & 7) << 2)) << 4); \
      af[i] = *(const s16x8*)(lds + byte); \
    } \
    _Pragma("unroll") \
    for (int j = 0; j < 4; j++) { \
      int n = wn * 64 + j * 16 + lr; \
      int byte = n * 64 + ((lk8 ^ ((n >> 1) & 3)) << 4); \
      bf[j] = *(const s16x8*)(ccur + byte); \
    } \
    __builtin_amdgcn_s_setprio(1); \
    _Pragma("unroll") \
    for (int i = 0; i < 2; i++) \
      _Pragma("unroll") \
      for (int j = 0; j < 4; j++) \
        acc2[i][j] = __builtin_amdgcn_mfma_f32_16x16x32_bf16(af[i], bf[j], acc2[i][j], 0, 0, 0); \
    __builtin_amdgcn_s_setprio(0); \
    CTX_CONV(cnxt, CIa, CIb, CIc, CId); \
    if (((T) & 7) == 7) { \
      int d0c = ((T) >> 3) * 256; \
      _Pragma("unroll") \
      for (int i = 0; i < 2; i++) \
        _Pragma("unroll") \
        for (int q = 0; q < 4; q++) { \
          int gl = lh * 64 + wm * 32 + i * 16 + rh + q; \
          _Pragma("unroll") \
          for (int j = 0; j < 4; j++) { \
            int gn = d0c + wn * 64 + j * 16 + lr; \
            Cp[((size_t)b * 128 + gl) * 1024 + gn] = f2bf(acc2[i][j][q]); \
            acc2[i][j][q] = 0.f; \
          } \
        } \
    } \
    VMCNT(4); \
    LGKM0(); \
    SBAR(); \
    SFENCE(); \
    { char* t_ = ccur; ccur = cnxt; cnxt = cnx2; cnx2 = t_; } }

    // prologue: tiles 0,1
    CTX_LOAD(0, vAa, vAb, vAc, vAd);
    SFENCE();
    CTX_LOAD(1, vBa, vBb, vBc, vBd);
    SFENCE();
    CTX_CONV(ccur, vAa, vAb, vAc, vAd);
    VMCNT(4);
    LGKM0();
    SBAR();
    SFENCE();
#pragma unroll 1
    for (int it = 0; it < 16; ++it) {
      int t0 = 2 * it;
      CTX_STEP(t0,     vBa, vBb, vBc, vBd, vAa, vAb, vAc, vAd);
      CTX_STEP(t0 + 1, vAa, vAb, vAc, vAd, vBa, vBb, vBc, vBd);
    }
#undef CTX_STEP
#undef CTX_CONV
#undef CTX_LOAD
  }
}

// ---------------- K10: out[m][n] = sum_k ctx[m][k]*Wv[n][k] + bv[n]/32 ----------------
__global__ __launch_bounds__(256, 3) void k_gemm_out(
    const unsigned short* __restrict__ A, const unsigned short* __restrict__ Bm,
    const float* __restrict__ bv, float* __restrict__ Out) {
  __shared__ __attribute__((aligned(16))) char lds[49152];
  int tid = threadIdx.x, l = tid & 63, w = tid >> 6;
  int wm = w >> 1, wn = w & 1;
  int rid = blockIdx.x;
  int xcd = rid & 7, lid = rid >> 3;
  int bm = (xcd * 16 + (lid >> 3)) * 128;
  int bn = (lid & 7) * 128;
  int lr = l & 15, lk8 = l >> 4;
  int sF = (lr >> 1) & 3;
  int srow = tid >> 2;
  int swz = (tid & 3) ^ ((tid >> 3) & 3);
  const unsigned short* a0 = A + (size_t)(bm + srow) * 1024 + swz * 8;
  const unsigned short* a1 = A + (size_t)(bm + 64 + srow) * 1024 + swz * 8;
  const unsigned short* b0 = Bm + (size_t)(bn + srow) * 1024 + swz * 8;
  const unsigned short* b1 = Bm + (size_t)(bn + 64 + srow) * 1024 + swz * 8;
  char* cur = &lds[0];
  char* nxt = &lds[16384];
  char* nx2 = &lds[32768];
  f32x4 acc[4][4] = {};

#define OUT_STEP(T) { \
    int kn = (((T) + 2 < 32) ? (T) + 2 : 31) * 32; \
    gload_lds16(a0 + kn, nx2 + w * 1024); \
    gload_lds16(a1 + kn, nx2 + 4096 + w * 1024); \
    gload_lds16(b0 + kn, nx2 + 8192 + w * 1024); \
    gload_lds16(b1 + kn, nx2 + 12288 + w * 1024); \
    SFENCE(); \
    s16x8 af[4], bf[4]; \
    _Pragma("unroll") \
    for (int i = 0; i < 4; i++) { \
      int byte = (wm * 64 + i * 16 + lr) * 64 + ((lk8 ^ sF) << 4); \
      af[i] = *(const s16x8*)(cur + byte); \
    } \
    _Pragma("unroll") \
    for (int i = 0; i < 4; i++) { \
      int byte = 8192 + (wn * 64 + i * 16 + lr) * 64 + ((lk8 ^ sF) << 4); \
      bf[i] = *(const s16x8*)(cur + byte); \
    } \
    __builtin_amdgcn_s_setprio(1); \
    _Pragma("unroll") \
    for (int i = 0; i < 4; i++) \
      _Pragma("unroll") \
      for (int j = 0; j < 4; j++) \
        acc[i][j] = __builtin_amdgcn_mfma_f32_16x16x32_bf16(af[i], bf[j], acc[i][j], 0, 0, 0); \
    __builtin_amdgcn_s_setprio(0); \
    VMCNT(4); \
    SBAR(); \
    SFENCE(); \
    { char* t_ = cur; cur = nxt; nxt = nx2; nx2 = t_; } }

  gload_lds16(a0, cur + w * 1024);
  gload_lds16(a1, cur + 4096 + w * 1024);
  gload_lds16(b0, cur + 8192 + w * 1024);
  gload_lds16(b1, cur + 12288 + w * 1024);
  SFENCE();
  gload_lds16(a0 + 32, nxt + w * 1024);
  gload_lds16(a1 + 32, nxt + 4096 + w * 1024);
  gload_lds16(b0 + 32, nxt + 8192 + w * 1024);
  gload_lds16(b1 + 32, nxt + 12288 + w * 1024);
  SFENCE();
  VMCNT(4);
  SBAR();
  SFENCE();

#pragma unroll 1
  for (int t = 0; t < 32; ++t) {
    OUT_STEP(t);
  }

  int rh = (l >> 4) * 4;
#pragma unroll
  for (int i = 0; i < 4; i++)
#pragma unroll
    for (int q = 0; q < 4; q++) {
      int gm = bm + wm * 64 + i * 16 + rh + q;
#pragma unroll
      for (int j = 0; j < 4; j++) {
        int gn = bn + wn * 64 + j * 16 + lr;
        Out[(size_t)gm * 1024 + gn] = acc[i][j][q] + 0.03125f * bv[gn];
      }
    }
#undef OUT_STEP
}

extern "C" void kernel_launch(void* const* d_in, const int* in_sizes, int n_in,
                              void* d_out, int out_size, void* d_ws, size_t ws_size,
                              hipStream_t stream) {
  const float* cap = (const float*)d_in[0];
  const float* img = (const float*)d_in[1];
  const float* Wq  = (const float*)d_in[2];
  const float* bq  = (const float*)d_in[3];
  const float* Wk  = (const float*)d_in[4];
  // d_in[5] = bk: constant across r -> cancels in softmax. Unused.
  const float* Wv  = (const float*)d_in[6];
  const float* bv  = (const float*)d_in[7];
  float* out = (float*)d_out;

  char* ws = (char*)d_ws;
  if (ws_size < 36700160ull) return;  // fail loudly (output stays poisoned)
  unsigned short* ctx = (unsigned short*)(ws);               // 32 MB
  float*          Qb  = (float*)(ws + 33554432);             // 512 KB
  unsigned short* QWh = (unsigned short*)(ws + 34078720);    // 256 KB
  unsigned short* QWl = (unsigned short*)(ws + 34340864);    // 256 KB
  unsigned short* Wvh = (unsigned short*)(ws + 34603008);    //   2 MB

  k_convert_hi<<<1024, 256, 0, stream>>>(Wv, Wvh, 1048576 / 4);
  // Q = cap @ Wq^T + bq  (f32)
  k_gemm_f32_tn<<<dim3(4, 32), 256, 0, stream>>>(cap, Wq, bq, Qb, 128, 1024, 1024);
  // QW = Q @ Wk  (f32 -> bf16 hi/lo)
  k_gemm_f32_nn_split<<<dim3(4, 32), 256, 0, stream>>>(Qb, Wk, QWh, QWl, 128, 1024, 1024);
  // fused: scores (3-pass split bf16) + softmax/32 + ctx = P @ img[b]
  k_fused<<<256, 512, 0, stream>>>(QWh, QWl, img, ctx);
  // out = ctx @ Wv^T + bv/32  (counted-vmcnt pipeline)
  k_gemm_out<<<1024, 256, 0, stream>>>(ctx, Wvh, bv, out);
}